// Round 2
// baseline (242.197 us; speedup 1.0000x reference)
//
#include <hip/hip_runtime.h>
#include <hip/hip_bf16.h>
#include <cstdint>
#include <cstddef>

typedef __attribute__((ext_vector_type(8))) short short8;
typedef __attribute__((ext_vector_type(4))) float f32x4;
typedef unsigned short u16;
typedef unsigned int u32;

#define B_ 2
#define C_ 2048
#define D_ 1024
#define H_ 16
#define HD_ 64

static __device__ __forceinline__ u16 f2b(float f) {
  u32 x = __builtin_bit_cast(u32, f);
  x += 0x7FFFu + ((x >> 16) & 1u);
  return (u16)(x >> 16);
}

// ---------------- plain convert f32 -> bf16 ----------------
__global__ void k_convert(const float* __restrict__ in, u16* __restrict__ out, int n) {
  int i = (blockIdx.x * blockDim.x + threadIdx.x) * 4;
  const int stride = gridDim.x * blockDim.x * 4;
  for (; i < n; i += stride) {
    float4 v = *reinterpret_cast<const float4*>(in + i);
    ushort4 o;
    o.x = f2b(v.x); o.y = f2b(v.y); o.z = f2b(v.z); o.w = f2b(v.w);
    *reinterpret_cast<ushort4*>(out + i) = o;
  }
}

// ---------------- transpose + convert: in[R][Cc] f32 -> out[Cc][R] bf16 ----------------
__global__ void k_tconv(const float* __restrict__ in, u16* __restrict__ out, int R, int Cc) {
  __shared__ float tile[64][65];
  const int tC = blockIdx.x * 64;
  const int tR = blockIdx.y * 64;
  const int t = threadIdx.x;
  const int r0 = t >> 4;         // 0..15
  const int c0 = (t & 15) * 4;   // 0..60
#pragma unroll
  for (int ii = 0; ii < 4; ++ii) {
    int r = ii * 16 + r0;
    float4 v = *reinterpret_cast<const float4*>(&in[(size_t)(tR + r) * Cc + tC + c0]);
    tile[r][c0] = v.x; tile[r][c0 + 1] = v.y; tile[r][c0 + 2] = v.z; tile[r][c0 + 3] = v.w;
  }
  __syncthreads();
#pragma unroll
  for (int ii = 0; ii < 4; ++ii) {
    int c = ii * 16 + r0;  // output row (= input col)
    ushort4 o;
    o.x = f2b(tile[c0 + 0][c]);
    o.y = f2b(tile[c0 + 1][c]);
    o.z = f2b(tile[c0 + 2][c]);
    o.w = f2b(tile[c0 + 3][c]);
    *reinterpret_cast<ushort4*>(&out[(size_t)(tC + c) * R + tR + c0]) = o;
  }
}

// ---------------- async global->LDS, 16B per lane ----------------
#define GLL16(gptr, lptr) __builtin_amdgcn_global_load_lds( \
    (const __attribute__((address_space(1))) u32*)(gptr),   \
    (__attribute__((address_space(3))) u32*)(lptr), 16, 0, 0)

// ---------------- BMx128 bf16 GEMM, C = A * Bt^T + bias ----------------
// EPI 0: scatter into Q/K/V [B,H,C,hd] bf16.  EPI 1: write f32 C + bias.
template<int EPI, int BM>
__global__ __launch_bounds__(256) void k_gemm(
    const u16* __restrict__ A, const u16* __restrict__ Bt,
    int M, int N, int K, const float* __restrict__ bias,
    u16* __restrict__ Cq, u16* __restrict__ Ck, u16* __restrict__ Cv,
    float* __restrict__ Cf)
{
  constexpr int WCW = (BM == 128) ? 64 : 32;   // per-wave col width
  constexpr int NF = WCW / 16;                 // n-frags per wave
  __shared__ __align__(16) u16 As[BM * 32];
  __shared__ __align__(16) u16 Bs[128 * 32];
  const int t = threadIdx.x;
  const int l = t & 63, w = t >> 6;
  const int wr = (BM == 128) ? (w >> 1) : 0;
  const int wc = (BM == 128) ? (w & 1) : w;
  const int lr = l & 15, lg = l >> 4;
  const int m0 = blockIdx.y * BM, n0 = blockIdx.x * 128;
  f32x4 acc[4][NF] = {};

  for (int k0 = 0; k0 < K; k0 += 32) {
#pragma unroll
    for (int s = 0; s < BM / 64; ++s) {
      const int f = s * 2048 + t * 8;
      const int row = f >> 5, col = f & 31;
      GLL16(A + (size_t)(m0 + row) * K + k0 + col, As + f);
    }
#pragma unroll
    for (int s = 0; s < 2; ++s) {
      const int f = s * 2048 + t * 8;
      const int row = f >> 5, col = f & 31;
      GLL16(Bt + (size_t)(n0 + row) * K + k0 + col, Bs + f);
    }
    __syncthreads();
    short8 af[4], bfr[NF];
#pragma unroll
    for (int m = 0; m < 4; ++m)
      af[m] = *reinterpret_cast<const short8*>(&As[(wr * 64 + m * 16 + lr) * 32 + lg * 8]);
#pragma unroll
    for (int n = 0; n < NF; ++n)
      bfr[n] = *reinterpret_cast<const short8*>(&Bs[(wc * WCW + n * 16 + lr) * 32 + lg * 8]);
#pragma unroll
    for (int m = 0; m < 4; ++m)
#pragma unroll
      for (int n = 0; n < NF; ++n)
        acc[m][n] = __builtin_amdgcn_mfma_f32_16x16x32_bf16(af[m], bfr[n], acc[m][n], 0, 0, 0);
    __syncthreads();
  }

#pragma unroll
  for (int m = 0; m < 4; ++m) {
    const int mg = m0 + wr * 64 + m * 16 + lg * 4;
#pragma unroll
    for (int n = 0; n < NF; ++n) {
      const int ng = n0 + wc * WCW + n * 16 + lr;
      const float bia = bias[ng];
      if (EPI == 0) {
        const int reg = ng >> 10, d = ng & 1023, h = d >> 6, e = d & 63;
        u16* dst = (reg == 0) ? Cq : ((reg == 1) ? Ck : Cv);
#pragma unroll
        for (int j = 0; j < 4; ++j) {
          const int mm = mg + j;
          const int b = mm >> 11, c = mm & 2047;
          dst[(((size_t)(b * H_ + h) * C_ + c) << 6) + e] = f2b(acc[m][n][j] + bia);
        }
      } else {
#pragma unroll
        for (int j = 0; j < 4; ++j)
          Cf[(size_t)(mg + j) * N + ng] = acc[m][n][j] + bia;
      }
    }
  }
}

// ---------------- V [BH][C][hd] -> Vt [BH][hd][C] ----------------
__global__ void k_vtrans(const u16* __restrict__ V, u16* __restrict__ Vt) {
  __shared__ __align__(16) u16 tl[64][72];
  const int bh = blockIdx.x >> 5;
  const int c0 = (blockIdx.x & 31) * 64;
  const int t = threadIdx.x;
#pragma unroll
  for (int ch = 0; ch < 2; ++ch) {
    const int idx = t + ch * 256;
    const int r = idx >> 3, c8 = (idx & 7) * 8;
    *reinterpret_cast<short8*>(&tl[r][c8]) =
        *reinterpret_cast<const short8*>(&V[((size_t)bh * C_ + c0 + r) * HD_ + c8]);
  }
  __syncthreads();
#pragma unroll
  for (int ch = 0; ch < 2; ++ch) {
    const int idx = t + ch * 256;
    const int d = idx >> 3, cc = (idx & 7) * 8;
    alignas(16) u16 tmp[8];
#pragma unroll
    for (int u = 0; u < 8; ++u) tmp[u] = tl[cc + u][d];
    *reinterpret_cast<short8*>(&Vt[((size_t)bh * HD_ + d) * C_ + c0 + cc]) =
        *reinterpret_cast<const short8*>(tmp);
  }
}

// ---------------- causal flash attention (v2: K dbuf, V direct, 1 barrier/iter) ----
// grid: 1024 blocks = (32 q-tiles reversed) x (32 bh); 256 thr = 4 waves x 16 q-rows
__global__ __launch_bounds__(256, 4) void k_attn(
    const u16* __restrict__ Q, const u16* __restrict__ Kb, const u16* __restrict__ Vt,
    const float* __restrict__ mask, u16* __restrict__ O)
{
  __shared__ __align__(16) u16 Kl[2][64 * 72];
  __shared__ __align__(16) u16 Pl[4][16 * 72];
  const int bid = blockIdx.x;
  const int bh = bid & 31;
  const int qt = 31 - (bid >> 5);          // big tiles first
  const int b = bh >> 4, h = bh & 15;
  const int t = threadIdx.x;
  const int l = t & 63, w = t >> 6;
  const int lr = l & 15, lg = l >> 4;
  const float scaling = 0.125f;            // hd^-0.5

  // K staging geometry: 2 chunks of short8 per thread cover 64x64
  const int sr0 = t >> 3, sc0 = (t & 7) * 8;   // rows 0..31 / 32..63
  const u16* kgb = Kb + ((size_t)bh * C_ + sr0) * HD_ + sc0;   // + kt*64*HD_ ; +32*HD_ for chunk1

  short8 aq[2];
  {
    const int qrow = qt * 64 + w * 16 + lr;
    const u16* qp = Q + ((size_t)bh * C_ + qrow) * HD_ + lg * 8;
    aq[0] = *reinterpret_cast<const short8*>(qp);
    aq[1] = *reinterpret_cast<const short8*>(qp + 32);
  }
  float mrun[4], srun[4];
  f32x4 oacc[4] = {};
#pragma unroll
  for (int j = 0; j < 4; ++j) { mrun[j] = -INFINITY; srun[j] = 0.f; }
  const int qrb = qt * 64 + w * 16 + lg * 4;
  u16* Pw = Pl[w];

  // V base: row = df*16+lr of Vt[bh], col base lg*8; per-tile add kt*64, s2 adds 32
  const u16* vbase = Vt + ((size_t)bh * HD_ + lr) * C_ + lg * 8;
  // mask base: row = qrb+j, col = lr; per-tile add kt*64, nf adds 16
  const float* mbase = mask + ((size_t)b * C_ + qrb) * C_ + lr;

  // ---- prologue: stage K tile 0 into buffer 0 ----
  {
    short8 k0 = *reinterpret_cast<const short8*>(kgb);
    short8 k1 = *reinterpret_cast<const short8*>(kgb + 32 * HD_);
    *reinterpret_cast<short8*>(&Kl[0][sr0 * 72 + sc0]) = k0;
    *reinterpret_cast<short8*>(&Kl[0][(sr0 + 32) * 72 + sc0]) = k1;
  }
  __syncthreads();

  for (int kt = 0; kt <= qt; ++kt) {
    const int cur = kt & 1;
    // A) issue next-K global loads (hidden under this iter's compute)
    short8 kn0, kn1;
    if (kt < qt) {
      const u16* kp = kgb + (size_t)(kt + 1) * 64 * HD_;
      kn0 = *reinterpret_cast<const short8*>(kp);
      kn1 = *reinterpret_cast<const short8*>(kp + 32 * HD_);
    }
    // B) issue V loads for this tile (direct from global, L2-resident)
    short8 bv[2][4];
#pragma unroll
    for (int s2 = 0; s2 < 2; ++s2)
#pragma unroll
      for (int df = 0; df < 4; ++df)
        bv[s2][df] = *reinterpret_cast<const short8*>(
            vbase + (size_t)df * 16 * C_ + kt * 64 + s2 * 32);
    // C) mask loads
    float mv[4][4];
#pragma unroll
    for (int nf = 0; nf < 4; ++nf)
#pragma unroll
      for (int j = 0; j < 4; ++j)
        mv[nf][j] = mbase[(size_t)j * C_ + kt * 64 + nf * 16];

    // D) S = Q K^T
    f32x4 sf[4] = {};
    __builtin_amdgcn_s_setprio(1);
#pragma unroll
    for (int s = 0; s < 2; ++s)
#pragma unroll
      for (int nf = 0; nf < 4; ++nf) {
        short8 bk = *reinterpret_cast<const short8*>(
            &Kl[cur][(nf * 16 + lr) * 72 + s * 32 + lg * 8]);
        sf[nf] = __builtin_amdgcn_mfma_f32_16x16x32_bf16(aq[s], bk, sf[nf], 0, 0, 0);
      }
    __builtin_amdgcn_s_setprio(0);

    // E) scale + mask (+ causal on diagonal only)
    float p[4][4];
    float pm[4] = {-INFINITY, -INFINITY, -INFINITY, -INFINITY};
    if (kt < qt) {
#pragma unroll
      for (int nf = 0; nf < 4; ++nf)
#pragma unroll
        for (int j = 0; j < 4; ++j) {
          const float v = fmaf(sf[nf][j], scaling, mv[nf][j]);
          p[nf][j] = v;
          pm[j] = fmaxf(pm[j], v);
        }
    } else {
#pragma unroll
      for (int nf = 0; nf < 4; ++nf) {
        const int key = kt * 64 + nf * 16 + lr;
#pragma unroll
        for (int j = 0; j < 4; ++j) {
          float v = fmaf(sf[nf][j], scaling, mv[nf][j]);
          if (key > qrb + j) v = -INFINITY;
          p[nf][j] = v;
          pm[j] = fmaxf(pm[j], v);
        }
      }
    }
    // online softmax (row lives in a 16-lane group)
#pragma unroll
    for (int j = 0; j < 4; ++j) {
      pm[j] = fmaxf(pm[j], __shfl_xor(pm[j], 1));
      pm[j] = fmaxf(pm[j], __shfl_xor(pm[j], 2));
      pm[j] = fmaxf(pm[j], __shfl_xor(pm[j], 4));
      pm[j] = fmaxf(pm[j], __shfl_xor(pm[j], 8));
    }
#pragma unroll
    for (int j = 0; j < 4; ++j) {
      const float mn = fmaxf(mrun[j], pm[j]);
      const float rescale = __expf(mrun[j] - mn);   // first iter: exp(-inf)=0
      float rsum = 0.f;
#pragma unroll
      for (int nf = 0; nf < 4; ++nf) {
        const float e = __expf(p[nf][j] - mn);
        p[nf][j] = e;
        rsum += e;
      }
      rsum += __shfl_xor(rsum, 1);
      rsum += __shfl_xor(rsum, 2);
      rsum += __shfl_xor(rsum, 4);
      rsum += __shfl_xor(rsum, 8);
      srun[j] = srun[j] * rescale + rsum;
      mrun[j] = mn;
#pragma unroll
      for (int df = 0; df < 4; ++df) oacc[df][j] *= rescale;
    }

    // F) P -> per-wave LDS (re-fragment), then PV from V regs
#pragma unroll
    for (int nf = 0; nf < 4; ++nf)
#pragma unroll
      for (int j = 0; j < 4; ++j)
        Pw[(lg * 4 + j) * 72 + nf * 16 + lr] = f2b(p[nf][j]);

    __builtin_amdgcn_s_setprio(1);
#pragma unroll
    for (int s2 = 0; s2 < 2; ++s2) {
      short8 ap = *reinterpret_cast<const short8*>(&Pw[lr * 72 + s2 * 32 + lg * 8]);
#pragma unroll
      for (int df = 0; df < 4; ++df)
        oacc[df] = __builtin_amdgcn_mfma_f32_16x16x32_bf16(ap, bv[s2][df], oacc[df], 0, 0, 0);
    }
    __builtin_amdgcn_s_setprio(0);

    // G) stage next K tile into the other buffer
    if (kt < qt) {
      *reinterpret_cast<short8*>(&Kl[cur ^ 1][sr0 * 72 + sc0]) = kn0;
      *reinterpret_cast<short8*>(&Kl[cur ^ 1][(sr0 + 32) * 72 + sc0]) = kn1;
    }
    __syncthreads();
  }

  // normalize + write attn_out [B,C,H,hd] bf16
#pragma unroll
  for (int df = 0; df < 4; ++df) {
    const int dcol = df * 16 + lr;
#pragma unroll
    for (int j = 0; j < 4; ++j) {
      const int qr = qrb + j;
      O[((size_t)b * C_ + qr) * D_ + h * HD_ + dcol] = f2b(oacc[df][j] / srun[j]);
    }
  }
}

extern "C" void kernel_launch(void* const* d_in, const int* in_sizes, int n_in,
                              void* d_out, int out_size, void* d_ws, size_t ws_size,
                              hipStream_t stream) {
  const float* hs   = (const float*)d_in[0];
  const float* mask = (const float*)d_in[1];
  const float* Wqkv = (const float*)d_in[2];
  const float* bqkv = (const float*)d_in[3];
  const float* Wo   = (const float*)d_in[4];
  const float* bo   = (const float*)d_in[5];
  float* out = (float*)d_out;
  char* ws = (char*)d_ws;

  u16* hsb   = (u16*)(ws);                 // 8 MB [4096][1024]
  u16* Wqkvt = (u16*)(ws + (8  << 20));    // 6 MB [3072][1024]
  u16* Wot   = (u16*)(ws + (14 << 20));    // 2 MB [1024][1024]
  u16* Qb    = (u16*)(ws + (16 << 20));    // 8 MB [2,16,2048,64]
  u16* Kb    = (u16*)(ws + (24 << 20));    // 8 MB
  u16* Vb    = (u16*)(ws + (32 << 20));    // 8 MB
  u16* Vtb   = (u16*)(ws + (40 << 20));    // 8 MB [2,16,64,2048]
  u16* AOb   = (u16*)(ws + (48 << 20));    // 8 MB [4096][1024]

  k_convert<<<2048, 256, 0, stream>>>(hs, hsb, 4096 * 1024);
  k_tconv<<<dim3(3072 / 64, 1024 / 64), 256, 0, stream>>>(Wqkv, Wqkvt, 1024, 3072);
  k_tconv<<<dim3(1024 / 64, 1024 / 64), 256, 0, stream>>>(Wo, Wot, 1024, 1024);
  k_gemm<0, 128><<<dim3(24, 32), 256, 0, stream>>>(hsb, Wqkvt, 4096, 3072, 1024, bqkv,
                                                   Qb, Kb, Vb, nullptr);
  k_vtrans<<<1024, 256, 0, stream>>>(Vb, Vtb);
  k_attn<<<1024, 256, 0, stream>>>(Qb, Kb, Vtb, mask, AOb);
  k_gemm<1, 64><<<dim3(8, 64), 256, 0, stream>>>(AOb, Wot, 4096, 1024, 1024, bo,
                                                 nullptr, nullptr, nullptr, out);
}

// Round 3
// 174.981 us; speedup vs baseline: 1.3841x; 1.3841x over previous
//
#include <hip/hip_runtime.h>
#include <hip/hip_bf16.h>
#include <cstdint>
#include <cstddef>

typedef __attribute__((ext_vector_type(8))) short short8;
typedef __attribute__((ext_vector_type(4))) float f32x4;
typedef unsigned short u16;
typedef unsigned int u32;

#define B_ 2
#define C_ 2048
#define D_ 1024
#define H_ 16
#define HD_ 64

static __device__ __forceinline__ u16 f2b(float f) {
  u32 x = __builtin_bit_cast(u32, f);
  x += 0x7FFFu + ((x >> 16) & 1u);
  return (u16)(x >> 16);
}

// ---------------- plain convert f32 -> bf16 ----------------
__global__ void k_convert(const float* __restrict__ in, u16* __restrict__ out, int n) {
  int i = (blockIdx.x * blockDim.x + threadIdx.x) * 4;
  const int stride = gridDim.x * blockDim.x * 4;
  for (; i < n; i += stride) {
    float4 v = *reinterpret_cast<const float4*>(in + i);
    ushort4 o;
    o.x = f2b(v.x); o.y = f2b(v.y); o.z = f2b(v.z); o.w = f2b(v.w);
    *reinterpret_cast<ushort4*>(out + i) = o;
  }
}

// ---------------- transpose + convert: in[R][Cc] f32 -> out[Cc][R] bf16 ----------------
__global__ void k_tconv(const float* __restrict__ in, u16* __restrict__ out, int R, int Cc) {
  __shared__ float tile[64][65];
  const int tC = blockIdx.x * 64;
  const int tR = blockIdx.y * 64;
  const int t = threadIdx.x;
  const int r0 = t >> 4;         // 0..15
  const int c0 = (t & 15) * 4;   // 0..60
#pragma unroll
  for (int ii = 0; ii < 4; ++ii) {
    int r = ii * 16 + r0;
    float4 v = *reinterpret_cast<const float4*>(&in[(size_t)(tR + r) * Cc + tC + c0]);
    tile[r][c0] = v.x; tile[r][c0 + 1] = v.y; tile[r][c0 + 2] = v.z; tile[r][c0 + 3] = v.w;
  }
  __syncthreads();
#pragma unroll
  for (int ii = 0; ii < 4; ++ii) {
    int c = ii * 16 + r0;  // output row (= input col)
    ushort4 o;
    o.x = f2b(tile[c0 + 0][c]);
    o.y = f2b(tile[c0 + 1][c]);
    o.z = f2b(tile[c0 + 2][c]);
    o.w = f2b(tile[c0 + 3][c]);
    *reinterpret_cast<ushort4*>(&out[(size_t)(tC + c) * R + tR + c0]) = o;
  }
}

// ---------------- async global->LDS, 16B per lane ----------------
#define GLL16(gptr, lptr) __builtin_amdgcn_global_load_lds( \
    (const __attribute__((address_space(1))) u32*)(gptr),   \
    (__attribute__((address_space(3))) u32*)(lptr), 16, 0, 0)

// ---------------- BMx128 bf16 GEMM, C = A * Bt^T + bias ----------------
// EPI 0: scatter into Q/K/V [B,H,C,hd] bf16.  EPI 1: write f32 C + bias.
template<int EPI, int BM>
__global__ __launch_bounds__(256) void k_gemm(
    const u16* __restrict__ A, const u16* __restrict__ Bt,
    int M, int N, int K, const float* __restrict__ bias,
    u16* __restrict__ Cq, u16* __restrict__ Ck, u16* __restrict__ Cv,
    float* __restrict__ Cf)
{
  constexpr int WCW = (BM == 128) ? 64 : 32;   // per-wave col width
  constexpr int NF = WCW / 16;                 // n-frags per wave
  __shared__ __align__(16) u16 As[BM * 32];
  __shared__ __align__(16) u16 Bs[128 * 32];
  const int t = threadIdx.x;
  const int l = t & 63, w = t >> 6;
  const int wr = (BM == 128) ? (w >> 1) : 0;
  const int wc = (BM == 128) ? (w & 1) : w;
  const int lr = l & 15, lg = l >> 4;
  const int m0 = blockIdx.y * BM, n0 = blockIdx.x * 128;
  f32x4 acc[4][NF] = {};

  for (int k0 = 0; k0 < K; k0 += 32) {
#pragma unroll
    for (int s = 0; s < BM / 64; ++s) {
      const int f = s * 2048 + t * 8;
      const int row = f >> 5, col = f & 31;
      GLL16(A + (size_t)(m0 + row) * K + k0 + col, As + f);
    }
#pragma unroll
    for (int s = 0; s < 2; ++s) {
      const int f = s * 2048 + t * 8;
      const int row = f >> 5, col = f & 31;
      GLL16(Bt + (size_t)(n0 + row) * K + k0 + col, Bs + f);
    }
    __syncthreads();
    short8 af[4], bfr[NF];
#pragma unroll
    for (int m = 0; m < 4; ++m)
      af[m] = *reinterpret_cast<const short8*>(&As[(wr * 64 + m * 16 + lr) * 32 + lg * 8]);
#pragma unroll
    for (int n = 0; n < NF; ++n)
      bfr[n] = *reinterpret_cast<const short8*>(&Bs[(wc * WCW + n * 16 + lr) * 32 + lg * 8]);
#pragma unroll
    for (int m = 0; m < 4; ++m)
#pragma unroll
      for (int n = 0; n < NF; ++n)
        acc[m][n] = __builtin_amdgcn_mfma_f32_16x16x32_bf16(af[m], bfr[n], acc[m][n], 0, 0, 0);
    __syncthreads();
  }

#pragma unroll
  for (int m = 0; m < 4; ++m) {
    const int mg = m0 + wr * 64 + m * 16 + lg * 4;
#pragma unroll
    for (int n = 0; n < NF; ++n) {
      const int ng = n0 + wc * WCW + n * 16 + lr;
      const float bia = bias[ng];
      if (EPI == 0) {
        const int reg = ng >> 10, d = ng & 1023, h = d >> 6, e = d & 63;
        u16* dst = (reg == 0) ? Cq : ((reg == 1) ? Ck : Cv);
#pragma unroll
        for (int j = 0; j < 4; ++j) {
          const int mm = mg + j;
          const int b = mm >> 11, c = mm & 2047;
          dst[(((size_t)(b * H_ + h) * C_ + c) << 6) + e] = f2b(acc[m][n][j] + bia);
        }
      } else {
#pragma unroll
        for (int j = 0; j < 4; ++j)
          Cf[(size_t)(mg + j) * N + ng] = acc[m][n][j] + bia;
      }
    }
  }
}

// ---------------- V [BH][C][hd] -> Vt [BH][hd][C] ----------------
__global__ void k_vtrans(const u16* __restrict__ V, u16* __restrict__ Vt) {
  __shared__ __align__(16) u16 tl[64][72];
  const int bh = blockIdx.x >> 5;
  const int c0 = (blockIdx.x & 31) * 64;
  const int t = threadIdx.x;
#pragma unroll
  for (int ch = 0; ch < 2; ++ch) {
    const int idx = t + ch * 256;
    const int r = idx >> 3, c8 = (idx & 7) * 8;
    *reinterpret_cast<short8*>(&tl[r][c8]) =
        *reinterpret_cast<const short8*>(&V[((size_t)bh * C_ + c0 + r) * HD_ + c8]);
  }
  __syncthreads();
#pragma unroll
  for (int ch = 0; ch < 2; ++ch) {
    const int idx = t + ch * 256;
    const int d = idx >> 3, cc = (idx & 7) * 8;
    alignas(16) u16 tmp[8];
#pragma unroll
    for (int u = 0; u < 8; ++u) tmp[u] = tl[cc + u][d];
    *reinterpret_cast<short8*>(&Vt[((size_t)bh * HD_ + d) * C_ + c0 + cc]) =
        *reinterpret_cast<const short8*>(tmp);
  }
}

// stage one 64x64 bf16 tile of K and of Vt into LDS via DMA, XOR-swizzled source.
// LDS unit (row, c) holds global unit (row, c ^ (row&7)); read side applies same XOR.
static __device__ __forceinline__ void stage_kv(
    const u16* __restrict__ Kbh, const u16* __restrict__ Vbh,
    u16* Kd, u16* Vd, int kt, int t)
{
#pragma unroll
  for (int ch = 0; ch < 2; ++ch) {
    const int u = ch * 256 + t;
    const int row = u >> 3;
    const int c16 = (u & 7) ^ (row & 7);
    GLL16(Kbh + (((size_t)(kt * 64 + row)) << 6) + (c16 << 3), Kd + (u << 3));
    GLL16(Vbh + (((size_t)row) << 11) + kt * 64 + (c16 << 3), Vd + (u << 3));
  }
}

// ---------------- causal flash attention (v3) ----------------
// grid: 512 blocks = 16 pairs x 32 bh; block does q-tiles {pair, 31-pair} => 33 KV-tiles each.
// 256 thr = 4 waves x 16 q-rows. K/V DMA-staged (dbuf, swizzled), 1 barrier/iter.
__global__ __launch_bounds__(256) void k_attn(
    const u16* __restrict__ Q, const u16* __restrict__ Kb, const u16* __restrict__ Vt,
    const float* __restrict__ mask, u16* __restrict__ O)
{
  __shared__ __align__(16) u16 Kl[2][64 * 64];
  __shared__ __align__(16) u16 Vl[2][64 * 64];
  __shared__ __align__(16) u16 Pl[4][16 * 72];
  const int bid = blockIdx.x;
  const int bh = bid & 31;               // fixed-bh blocks share an XCD (bid%8 == bh%8)
  const int pair = bid >> 5;             // 0..15
  const int b = bh >> 4, h = bh & 15;
  const int t = threadIdx.x;
  const int l = t & 63, w = t >> 6;
  const int lr = l & 15, lg = l >> 4;
  const int sw = lr & 7;                 // read-side swizzle key
  const float scaling = 0.125f;          // hd^-0.5

  const u16* Kbh = Kb + (size_t)bh * C_ * HD_;
  const u16* Vbh = Vt + (size_t)bh * HD_ * C_;
  u16* Pw = Pl[w];

#pragma unroll 1
  for (int phase = 0; phase < 2; ++phase) {
    const int qt = phase ? (31 - pair) : pair;
    const int qrb = qt * 64 + w * 16 + lg * 4;

    short8 aq[2];
    {
      const int qrow = qt * 64 + w * 16 + lr;
      const u16* qp = Q + ((size_t)bh * C_ + qrow) * HD_ + lg * 8;
      aq[0] = *reinterpret_cast<const short8*>(qp);
      aq[1] = *reinterpret_cast<const short8*>(qp + 32);
    }
    float mrun[4], srun[4];
    f32x4 oacc[4] = {};
#pragma unroll
    for (int j = 0; j < 4; ++j) { mrun[j] = -INFINITY; srun[j] = 0.f; }
    const float* mbase = mask + ((size_t)b * C_ + qrb) * C_ + lr;

    __builtin_amdgcn_s_barrier();        // prev phase readers done before buf0 overwrite
    stage_kv(Kbh, Vbh, Kl[0], Vl[0], 0, t);

    for (int kt = 0; kt <= qt; ++kt) {
      const int cur = kt & 1;
      asm volatile("s_waitcnt vmcnt(0)" ::: "memory");  // own DMA for tile kt done
      __builtin_amdgcn_s_barrier();                     // all waves' DMA done

      // mask loads early (hide under QK)
      float mv[4][4];
#pragma unroll
      for (int nf = 0; nf < 4; ++nf)
#pragma unroll
        for (int j = 0; j < 4; ++j)
          mv[nf][j] = mbase[(size_t)j * C_ + kt * 64 + nf * 16];

      // S = Q K^T (swizzled K reads)
      f32x4 sf[4] = {};
      __builtin_amdgcn_s_setprio(1);
#pragma unroll
      for (int s = 0; s < 2; ++s)
#pragma unroll
        for (int nf = 0; nf < 4; ++nf) {
          const short8 bk = *reinterpret_cast<const short8*>(
              &Kl[cur][((nf * 16 + lr) << 6) + (((s * 4 + lg) ^ sw) << 3)]);
          sf[nf] = __builtin_amdgcn_mfma_f32_16x16x32_bf16(aq[s], bk, sf[nf], 0, 0, 0);
        }
      __builtin_amdgcn_s_setprio(0);

      // prefetch next tile: DMA flies under softmax + PV, drained at next iter top
      if (kt < qt) stage_kv(Kbh, Vbh, Kl[cur ^ 1], Vl[cur ^ 1], kt + 1, t);

      // scale + mask (+ causal only on the diagonal tile)
      float p[4][4];
      float pm[4] = {-INFINITY, -INFINITY, -INFINITY, -INFINITY};
      if (kt < qt) {
#pragma unroll
        for (int nf = 0; nf < 4; ++nf)
#pragma unroll
          for (int j = 0; j < 4; ++j) {
            const float v = fmaf(sf[nf][j], scaling, mv[nf][j]);
            p[nf][j] = v;
            pm[j] = fmaxf(pm[j], v);
          }
      } else {
#pragma unroll
        for (int nf = 0; nf < 4; ++nf) {
          const int key = kt * 64 + nf * 16 + lr;
#pragma unroll
          for (int j = 0; j < 4; ++j) {
            float v = fmaf(sf[nf][j], scaling, mv[nf][j]);
            if (key > qrb + j) v = -INFINITY;
            p[nf][j] = v;
            pm[j] = fmaxf(pm[j], v);
          }
        }
      }
      // online softmax (row lives in a 16-lane group)
#pragma unroll
      for (int j = 0; j < 4; ++j) {
        pm[j] = fmaxf(pm[j], __shfl_xor(pm[j], 1));
        pm[j] = fmaxf(pm[j], __shfl_xor(pm[j], 2));
        pm[j] = fmaxf(pm[j], __shfl_xor(pm[j], 4));
        pm[j] = fmaxf(pm[j], __shfl_xor(pm[j], 8));
      }
#pragma unroll
      for (int j = 0; j < 4; ++j) {
        const float mn = fmaxf(mrun[j], pm[j]);
        const float rescale = __expf(mrun[j] - mn);   // first iter: exp(-inf)=0
        float rsum = 0.f;
#pragma unroll
        for (int nf = 0; nf < 4; ++nf) {
          const float e = __expf(p[nf][j] - mn);
          p[nf][j] = e;
          rsum += e;
        }
        rsum += __shfl_xor(rsum, 1);
        rsum += __shfl_xor(rsum, 2);
        rsum += __shfl_xor(rsum, 4);
        rsum += __shfl_xor(rsum, 8);
        srun[j] = srun[j] * rescale + rsum;
        mrun[j] = mn;
#pragma unroll
        for (int df = 0; df < 4; ++df) oacc[df][j] *= rescale;
      }

      // P -> per-wave LDS (private to this wave: no barrier needed)
#pragma unroll
      for (int nf = 0; nf < 4; ++nf)
#pragma unroll
        for (int j = 0; j < 4; ++j)
          Pw[(lg * 4 + j) * 72 + nf * 16 + lr] = f2b(p[nf][j]);

      // O += P V (swizzled V reads)
      __builtin_amdgcn_s_setprio(1);
#pragma unroll
      for (int s2 = 0; s2 < 2; ++s2) {
        const short8 ap = *reinterpret_cast<const short8*>(&Pw[lr * 72 + s2 * 32 + lg * 8]);
#pragma unroll
        for (int df = 0; df < 4; ++df) {
          const short8 bv = *reinterpret_cast<const short8*>(
              &Vl[cur][((df * 16 + lr) << 6) + (((s2 * 4 + lg) ^ sw) << 3)]);
          oacc[df] = __builtin_amdgcn_mfma_f32_16x16x32_bf16(ap, bv, oacc[df], 0, 0, 0);
        }
      }
      __builtin_amdgcn_s_setprio(0);
    }

    // normalize + write attn_out [B,C,H,hd] bf16
#pragma unroll
    for (int df = 0; df < 4; ++df) {
      const int dcol = df * 16 + lr;
#pragma unroll
      for (int j = 0; j < 4; ++j) {
        const int qr = qrb + j;
        O[((size_t)b * C_ + qr) * D_ + h * HD_ + dcol] = f2b(oacc[df][j] / srun[j]);
      }
    }
  }
}

extern "C" void kernel_launch(void* const* d_in, const int* in_sizes, int n_in,
                              void* d_out, int out_size, void* d_ws, size_t ws_size,
                              hipStream_t stream) {
  const float* hs   = (const float*)d_in[0];
  const float* mask = (const float*)d_in[1];
  const float* Wqkv = (const float*)d_in[2];
  const float* bqkv = (const float*)d_in[3];
  const float* Wo   = (const float*)d_in[4];
  const float* bo   = (const float*)d_in[5];
  float* out = (float*)d_out;
  char* ws = (char*)d_ws;

  u16* hsb   = (u16*)(ws);                 // 8 MB [4096][1024]
  u16* Wqkvt = (u16*)(ws + (8  << 20));    // 6 MB [3072][1024]
  u16* Wot   = (u16*)(ws + (14 << 20));    // 2 MB [1024][1024]
  u16* Qb    = (u16*)(ws + (16 << 20));    // 8 MB [2,16,2048,64]
  u16* Kb    = (u16*)(ws + (24 << 20));    // 8 MB
  u16* Vb    = (u16*)(ws + (32 << 20));    // 8 MB
  u16* Vtb   = (u16*)(ws + (40 << 20));    // 8 MB [2,16,64,2048]
  u16* AOb   = (u16*)(ws + (48 << 20));    // 8 MB [4096][1024]

  k_convert<<<2048, 256, 0, stream>>>(hs, hsb, 4096 * 1024);
  k_tconv<<<dim3(3072 / 64, 1024 / 64), 256, 0, stream>>>(Wqkv, Wqkvt, 1024, 3072);
  k_tconv<<<dim3(1024 / 64, 1024 / 64), 256, 0, stream>>>(Wo, Wot, 1024, 1024);
  k_gemm<0, 128><<<dim3(24, 32), 256, 0, stream>>>(hsb, Wqkvt, 4096, 3072, 1024, bqkv,
                                                   Qb, Kb, Vb, nullptr);
  k_vtrans<<<1024, 256, 0, stream>>>(Vb, Vtb);
  k_attn<<<512, 256, 0, stream>>>(Qb, Kb, Vtb, mask, AOb);
  k_gemm<1, 64><<<dim3(8, 64), 256, 0, stream>>>(AOb, Wot, 4096, 1024, 1024, bo,
                                                 nullptr, nullptr, nullptr, out);
}

// Round 4
// 154.046 us; speedup vs baseline: 1.5722x; 1.1359x over previous
//
#include <hip/hip_runtime.h>
#include <hip/hip_bf16.h>
#include <cstdint>
#include <cstddef>

typedef __attribute__((ext_vector_type(8))) short short8;
typedef __attribute__((ext_vector_type(4))) float f32x4;
typedef unsigned short u16;
typedef unsigned int u32;

#define B_ 2
#define C_ 2048
#define D_ 1024
#define H_ 16
#define HD_ 64

static __device__ __forceinline__ u16 f2b(float f) {
  u32 x = __builtin_bit_cast(u32, f);
  x += 0x7FFFu + ((x >> 16) & 1u);
  return (u16)(x >> 16);
}

// ---------------- plain convert f32 -> bf16 ----------------
__global__ void k_convert(const float* __restrict__ in, u16* __restrict__ out, int n) {
  int i = (blockIdx.x * blockDim.x + threadIdx.x) * 4;
  const int stride = gridDim.x * blockDim.x * 4;
  for (; i < n; i += stride) {
    float4 v = *reinterpret_cast<const float4*>(in + i);
    ushort4 o;
    o.x = f2b(v.x); o.y = f2b(v.y); o.z = f2b(v.z); o.w = f2b(v.w);
    *reinterpret_cast<ushort4*>(out + i) = o;
  }
}

// ---------------- transpose + convert: in[R][Cc] f32 -> out[Cc][R] bf16 ----------------
__global__ void k_tconv(const float* __restrict__ in, u16* __restrict__ out, int R, int Cc) {
  __shared__ float tile[64][65];
  const int tC = blockIdx.x * 64;
  const int tR = blockIdx.y * 64;
  const int t = threadIdx.x;
  const int r0 = t >> 4;         // 0..15
  const int c0 = (t & 15) * 4;   // 0..60
#pragma unroll
  for (int ii = 0; ii < 4; ++ii) {
    int r = ii * 16 + r0;
    float4 v = *reinterpret_cast<const float4*>(&in[(size_t)(tR + r) * Cc + tC + c0]);
    tile[r][c0] = v.x; tile[r][c0 + 1] = v.y; tile[r][c0 + 2] = v.z; tile[r][c0 + 3] = v.w;
  }
  __syncthreads();
#pragma unroll
  for (int ii = 0; ii < 4; ++ii) {
    int c = ii * 16 + r0;  // output row (= input col)
    ushort4 o;
    o.x = f2b(tile[c0 + 0][c]);
    o.y = f2b(tile[c0 + 1][c]);
    o.z = f2b(tile[c0 + 2][c]);
    o.w = f2b(tile[c0 + 3][c]);
    *reinterpret_cast<ushort4*>(&out[(size_t)(tC + c) * R + tR + c0]) = o;
  }
}

// ---------------- per-tile mask nonzero flags ----------------
// block = ((b*32)+qt)*16+kt ; tile = mask[b][0][qt*64..+63][kt*128..+127]
__global__ void k_maskflags(const float* __restrict__ mask, u32* __restrict__ flags) {
  const int bid = blockIdx.x;
  const int kt = bid & 15, qt = (bid >> 4) & 31, b = bid >> 9;
  const int t = threadIdx.x;
  const float* base = mask + ((size_t)b * C_ + qt * 64) * C_ + kt * 128;
  const int row = t >> 2, c0 = (t & 3) * 32;
  int any = 0;
#pragma unroll
  for (int i = 0; i < 8; ++i) {
    float4 v = *reinterpret_cast<const float4*>(base + (size_t)row * C_ + c0 + i * 4);
    any |= (v.x != 0.f) | (v.y != 0.f) | (v.z != 0.f) | (v.w != 0.f);
  }
  __shared__ int sh[4];
  const unsigned long long bal = __ballot(any);
  if ((t & 63) == 0) sh[t >> 6] = (bal != 0ull);
  __syncthreads();
  if (t == 0) flags[bid] = (u32)(sh[0] | sh[1] | sh[2] | sh[3]);
}

// ---------------- async global->LDS, 16B per lane ----------------
#define GLL16(gptr, lptr) __builtin_amdgcn_global_load_lds( \
    (const __attribute__((address_space(1))) u32*)(gptr),   \
    (__attribute__((address_space(3))) u32*)(lptr), 16, 0, 0)

// ---------------- BMx128 bf16 GEMM (BK=64, swizzled LDS), C = A * Bt^T + bias ----
// EPI 0: scatter Q/K -> [B,H,C,hd], V -> transposed [B,H,hd,C].  EPI 1: f32 C + bias.
template<int EPI, int BM>
__global__ __launch_bounds__(256) void k_gemm(
    const u16* __restrict__ A, const u16* __restrict__ Bt,
    int M, int N, int K, const float* __restrict__ bias,
    u16* __restrict__ Cq, u16* __restrict__ Ck, u16* __restrict__ Cv,
    float* __restrict__ Cf)
{
  constexpr int WCW = (BM == 128) ? 64 : 32;   // per-wave col width
  constexpr int NF = WCW / 16;                 // n-frags per wave
  __shared__ __align__(16) u16 As[BM * 64];
  __shared__ __align__(16) u16 Bs[128 * 64];
  const int t = threadIdx.x;
  const int l = t & 63, w = t >> 6;
  const int wr = (BM == 128) ? (w >> 1) : 0;
  const int wc = (BM == 128) ? (w & 1) : w;
  const int lr = l & 15, lg = l >> 4;
  const int swk = lr & 7;
  const int m0 = blockIdx.y * BM, n0 = blockIdx.x * 128;
  f32x4 acc[4][NF] = {};

  for (int k0 = 0; k0 < K; k0 += 64) {
#pragma unroll
    for (int s = 0; s < BM / 32; ++s) {        // A: BM*8 16B-units
      const int u = s * 256 + t;
      const int row = u >> 3, slot = (u & 7) ^ (row & 7);
      GLL16(A + (size_t)(m0 + row) * K + k0 + (slot << 3), As + (u << 3));
    }
#pragma unroll
    for (int s = 0; s < 4; ++s) {              // B: 1024 16B-units
      const int u = s * 256 + t;
      const int row = u >> 3, slot = (u & 7) ^ (row & 7);
      GLL16(Bt + (size_t)(n0 + row) * K + k0 + (slot << 3), Bs + (u << 3));
    }
    __syncthreads();
    short8 af[2][4], bfr[2][NF];
#pragma unroll
    for (int s = 0; s < 2; ++s) {
#pragma unroll
      for (int m = 0; m < 4; ++m)
        af[s][m] = *reinterpret_cast<const short8*>(
            &As[((wr * 64 + m * 16 + lr) << 6) + (((s * 4 + lg) ^ swk) << 3)]);
#pragma unroll
      for (int n = 0; n < NF; ++n)
        bfr[s][n] = *reinterpret_cast<const short8*>(
            &Bs[((wc * WCW + n * 16 + lr) << 6) + (((s * 4 + lg) ^ swk) << 3)]);
    }
#pragma unroll
    for (int s = 0; s < 2; ++s)
#pragma unroll
      for (int m = 0; m < 4; ++m)
#pragma unroll
        for (int n = 0; n < NF; ++n)
          acc[m][n] = __builtin_amdgcn_mfma_f32_16x16x32_bf16(af[s][m], bfr[s][n], acc[m][n], 0, 0, 0);
    __syncthreads();
  }

#pragma unroll
  for (int m = 0; m < 4; ++m) {
    const int mg = m0 + wr * 64 + m * 16 + lg * 4;
    const int bq = mg >> 11, c0 = mg & 2047;
#pragma unroll
    for (int n = 0; n < NF; ++n) {
      const int ng = n0 + wc * WCW + n * 16 + lr;
      const float bia = bias[ng];
      if (EPI == 0) {
        const int reg = ng >> 10, d = ng & 1023, h = d >> 6, e = d & 63;
        if (reg == 2) {
          u16* vp = Cv + (((size_t)(bq * H_ + h) * HD_ + e) << 11) + c0;  // [B,H,hd,C]
#pragma unroll
          for (int j = 0; j < 4; ++j) vp[j] = f2b(acc[m][n][j] + bia);
        } else {
          u16* dst = (reg == 0) ? Cq : Ck;
#pragma unroll
          for (int j = 0; j < 4; ++j)
            dst[(((size_t)(bq * H_ + h) * C_ + c0 + j) << 6) + e] = f2b(acc[m][n][j] + bia);
        }
      } else {
#pragma unroll
        for (int j = 0; j < 4; ++j)
          Cf[(size_t)(mg + j) * N + ng] = acc[m][n][j] + bia;
      }
    }
  }
}

// stage one K tile [128 keys][64 hd] and one Vt tile [64 hd][128 keys] via DMA.
// LDS linear; source col-slot pre-XOR-swizzled (T21): slot ^= row&7.
static __device__ __forceinline__ void stage_kv(
    const u16* __restrict__ Kbh, const u16* __restrict__ Vbh,
    u16* Kd, u16* Vd, int kt, int t)
{
#pragma unroll
  for (int ch = 0; ch < 4; ++ch) {
    const int u = ch * 256 + t;
    const int krow = u >> 3, kslot = (u & 7) ^ (krow & 7);
    GLL16(Kbh + (((size_t)(kt * 128 + krow)) << 6) + (kslot << 3), Kd + (u << 3));
    const int vrow = u >> 4, vslot = (u & 15) ^ (vrow & 7);
    GLL16(Vbh + (((size_t)vrow) << 11) + kt * 128 + (vslot << 3), Vd + (u << 3));
  }
}

// ---------------- causal flash attention (v4: KVBLK=128) ----------------
// grid: 512 = 16 pairs x 32 bh; block does q-tiles {pair, 31-pair} => 17 KV-iters each.
// 256 thr = 4 waves x 16 q-rows. K/V DMA dbuf (swizzled), P swizzled, 1 barrier/iter.
__global__ __launch_bounds__(256) void k_attn(
    const u16* __restrict__ Q, const u16* __restrict__ Kb, const u16* __restrict__ Vt,
    const float* __restrict__ mask, const u32* __restrict__ flags, u16* __restrict__ O)
{
  __shared__ __align__(16) u16 Kl[2][128 * 64];
  __shared__ __align__(16) u16 Vl[2][64 * 128];
  __shared__ __align__(16) u16 Pl[4][16 * 128];
  const int bid = blockIdx.x;
  const int bh = bid & 31;               // bid%8 == bh%8 -> per-XCD K/V locality
  const int pair = bid >> 5;             // 0..15
  const int b = bh >> 4, h = bh & 15;
  const int t = threadIdx.x;
  const int l = t & 63, w = t >> 6;
  const int lr = l & 15, lg = l >> 4;
  const int swk = lr & 7;
  const float scaling = 0.125f;          // hd^-0.5

  const u16* Kbh = Kb + (size_t)bh * C_ * HD_;
  const u16* Vbh = Vt + (size_t)bh * HD_ * C_;
  u16* Pw = Pl[w];

#pragma unroll 1
  for (int phase = 0; phase < 2; ++phase) {
    const int qt = phase ? (31 - pair) : pair;
    const int ktmax = qt >> 1;
    const int qrb = qt * 64 + w * 16 + lg * 4;

    short8 aq[2];
    {
      const int qrow = qt * 64 + w * 16 + lr;
      const u16* qp = Q + ((size_t)bh * C_ + qrow) * HD_ + lg * 8;
      aq[0] = *reinterpret_cast<const short8*>(qp);
      aq[1] = *reinterpret_cast<const short8*>(qp + 32);
    }
    float mrun[4], srun[4];
    f32x4 oacc[4] = {};
#pragma unroll
    for (int j = 0; j < 4; ++j) { mrun[j] = -INFINITY; srun[j] = 0.f; }
    const float* mbase = mask + ((size_t)b * C_ + qrb) * C_ + lr;
    const u32* fbase = flags + ((b << 5) + qt) * 16;

    __builtin_amdgcn_s_barrier();        // prev phase readers done before buf0 overwrite
    stage_kv(Kbh, Vbh, Kl[0], Vl[0], 0, t);

    for (int kt = 0; kt <= ktmax; ++kt) {
      const int cur = kt & 1;
      asm volatile("s_waitcnt vmcnt(0)" ::: "memory");  // own DMA for tile kt done
      __builtin_amdgcn_s_barrier();                     // all waves' DMA done

      const u32 mflag = fbase[kt];       // uniform scalar load

      // S = Q K^T (swizzled K reads)
      f32x4 sf[8] = {};
      __builtin_amdgcn_s_setprio(1);
#pragma unroll
      for (int s = 0; s < 2; ++s)
#pragma unroll
        for (int nf = 0; nf < 8; ++nf) {
          const short8 bk = *reinterpret_cast<const short8*>(
              &Kl[cur][((nf * 16 + lr) << 6) + (((s * 4 + lg) ^ swk) << 3)]);
          sf[nf] = __builtin_amdgcn_mfma_f32_16x16x32_bf16(aq[s], bk, sf[nf], 0, 0, 0);
        }
      __builtin_amdgcn_s_setprio(0);

      // prefetch next tile under softmax+PV
      if (kt < ktmax) stage_kv(Kbh, Vbh, Kl[cur ^ 1], Vl[cur ^ 1], kt + 1, t);

      // scale (+ mask only when tile has nonzeros)
      if (mflag) {
#pragma unroll
        for (int nf = 0; nf < 8; ++nf)
#pragma unroll
          for (int j = 0; j < 4; ++j)
            sf[nf][j] = fmaf(sf[nf][j], scaling, mbase[(size_t)j * C_ + kt * 128 + nf * 16]);
      } else {
#pragma unroll
        for (int nf = 0; nf < 8; ++nf)
#pragma unroll
          for (int j = 0; j < 4; ++j)
            sf[nf][j] *= scaling;
      }
      if (kt == ktmax) {                 // causal clamp on the diagonal tile
#pragma unroll
        for (int nf = 0; nf < 8; ++nf) {
          const int key = kt * 128 + nf * 16 + lr;
#pragma unroll
          for (int j = 0; j < 4; ++j)
            if (key > qrb + j) sf[nf][j] = -INFINITY;
        }
      }

      // online softmax (q-row lives in 16 lanes: shfl-xor 1,2,4,8)
      float pm[4] = {-INFINITY, -INFINITY, -INFINITY, -INFINITY};
#pragma unroll
      for (int nf = 0; nf < 8; ++nf)
#pragma unroll
        for (int j = 0; j < 4; ++j) pm[j] = fmaxf(pm[j], sf[nf][j]);
#pragma unroll
      for (int j = 0; j < 4; ++j) {
        pm[j] = fmaxf(pm[j], __shfl_xor(pm[j], 1));
        pm[j] = fmaxf(pm[j], __shfl_xor(pm[j], 2));
        pm[j] = fmaxf(pm[j], __shfl_xor(pm[j], 4));
        pm[j] = fmaxf(pm[j], __shfl_xor(pm[j], 8));
      }
#pragma unroll
      for (int j = 0; j < 4; ++j) {
        const float mn = fmaxf(mrun[j], pm[j]);
        const float rescale = __expf(mrun[j] - mn);   // first iter: exp(-inf)=0
        float rsum = 0.f;
#pragma unroll
        for (int nf = 0; nf < 8; ++nf) {
          const float e = __expf(sf[nf][j] - mn);
          sf[nf][j] = e;
          rsum += e;
        }
        rsum += __shfl_xor(rsum, 1);
        rsum += __shfl_xor(rsum, 2);
        rsum += __shfl_xor(rsum, 4);
        rsum += __shfl_xor(rsum, 8);
        srun[j] = srun[j] * rescale + rsum;
        mrun[j] = mn;
#pragma unroll
        for (int df = 0; df < 4; ++df) oacc[df][j] *= rescale;
      }

      // P -> per-wave LDS, XOR-swizzled (row=lg*4+j, col=nf*16+lr)
#pragma unroll
      for (int j = 0; j < 4; ++j) {
        const int prow = lg * 4 + j;
        const int psw = (prow & 7) << 3;
#pragma unroll
        for (int nf = 0; nf < 8; ++nf)
          Pw[(prow << 7) + ((nf * 16 + lr) ^ psw)] = f2b(sf[nf][j]);
      }

      // O += P V (swizzled P + V reads)
      __builtin_amdgcn_s_setprio(1);
#pragma unroll
      for (int s2 = 0; s2 < 4; ++s2) {
        const short8 ap = *reinterpret_cast<const short8*>(
            &Pw[(lr << 7) + (((s2 * 4 + lg) ^ swk) << 3)]);
#pragma unroll
        for (int df = 0; df < 4; ++df) {
          const short8 bv = *reinterpret_cast<const short8*>(
              &Vl[cur][((df * 16 + lr) << 7) + (((s2 * 4 + lg) ^ swk) << 3)]);
          oacc[df] = __builtin_amdgcn_mfma_f32_16x16x32_bf16(ap, bv, oacc[df], 0, 0, 0);
        }
      }
      __builtin_amdgcn_s_setprio(0);
    }

    // normalize + write attn_out [B,C,H*hd] bf16
    float rinv[4];
#pragma unroll
    for (int j = 0; j < 4; ++j) rinv[j] = 1.f / srun[j];
#pragma unroll
    for (int df = 0; df < 4; ++df) {
      const int dcol = df * 16 + lr;
#pragma unroll
      for (int j = 0; j < 4; ++j)
        O[((size_t)b * C_ + qrb + j) * D_ + h * HD_ + dcol] = f2b(oacc[df][j] * rinv[j]);
    }
  }
}

extern "C" void kernel_launch(void* const* d_in, const int* in_sizes, int n_in,
                              void* d_out, int out_size, void* d_ws, size_t ws_size,
                              hipStream_t stream) {
  const float* hs   = (const float*)d_in[0];
  const float* mask = (const float*)d_in[1];
  const float* Wqkv = (const float*)d_in[2];
  const float* bqkv = (const float*)d_in[3];
  const float* Wo   = (const float*)d_in[4];
  const float* bo   = (const float*)d_in[5];
  float* out = (float*)d_out;
  char* ws = (char*)d_ws;

  u16* hsb   = (u16*)(ws);                 // 8 MB [4096][1024]
  u16* Wqkvt = (u16*)(ws + (8  << 20));    // 6 MB [3072][1024]
  u16* Wot   = (u16*)(ws + (14 << 20));    // 2 MB [1024][1024]
  u16* Qb    = (u16*)(ws + (16 << 20));    // 8 MB [2,16,2048,64]
  u16* Kb    = (u16*)(ws + (24 << 20));    // 8 MB [2,16,2048,64]
  u32* flags = (u32*)(ws + (32 << 20));    // 4 KB [2][32][16]
  u16* Vtb   = (u16*)(ws + (40 << 20));    // 8 MB [2,16,64,2048]
  u16* AOb   = (u16*)(ws + (48 << 20));    // 8 MB [4096][1024]

  k_convert<<<2048, 256, 0, stream>>>(hs, hsb, 4096 * 1024);
  k_tconv<<<dim3(3072 / 64, 1024 / 64), 256, 0, stream>>>(Wqkv, Wqkvt, 1024, 3072);
  k_tconv<<<dim3(1024 / 64, 1024 / 64), 256, 0, stream>>>(Wo, Wot, 1024, 1024);
  k_maskflags<<<1024, 256, 0, stream>>>(mask, flags);
  k_gemm<0, 128><<<dim3(24, 32), 256, 0, stream>>>(hsb, Wqkvt, 4096, 3072, 1024, bqkv,
                                                   Qb, Kb, Vtb, nullptr);
  k_attn<<<512, 256, 0, stream>>>(Qb, Kb, Vtb, mask, flags, AOb);
  k_gemm<1, 64><<<dim3(8, 64), 256, 0, stream>>>(AOb, Wot, 4096, 1024, 1024, bo,
                                                 nullptr, nullptr, nullptr, out);
}

// Round 6
// 137.723 us; speedup vs baseline: 1.7586x; 1.1185x over previous
//
#include <hip/hip_runtime.h>
#include <hip/hip_bf16.h>
#include <cstdint>
#include <cstddef>

typedef __attribute__((ext_vector_type(8))) short short8;
typedef __attribute__((ext_vector_type(4))) float f32x4;
typedef __attribute__((ext_vector_type(16))) float f32x16;
typedef unsigned short u16;
typedef unsigned int u32;

#define B_ 2
#define C_ 2048
#define D_ 1024
#define H_ 16
#define HD_ 64

static __device__ __forceinline__ u16 f2b(float f) {
  u32 x = __builtin_bit_cast(u32, f);
  x += 0x7FFFu + ((x >> 16) & 1u);
  return (u16)(x >> 16);
}

// ---------------- plain convert f32 -> bf16 ----------------
__global__ void k_convert(const float* __restrict__ in, u16* __restrict__ out, int n) {
  int i = (blockIdx.x * blockDim.x + threadIdx.x) * 4;
  const int stride = gridDim.x * blockDim.x * 4;
  for (; i < n; i += stride) {
    float4 v = *reinterpret_cast<const float4*>(in + i);
    ushort4 o;
    o.x = f2b(v.x); o.y = f2b(v.y); o.z = f2b(v.z); o.w = f2b(v.w);
    *reinterpret_cast<ushort4*>(out + i) = o;
  }
}

// ---------------- transpose + convert: in[R][Cc] f32 -> out[Cc][R] bf16 ----------------
__global__ void k_tconv(const float* __restrict__ in, u16* __restrict__ out, int R, int Cc) {
  __shared__ float tile[64][65];
  const int tC = blockIdx.x * 64;
  const int tR = blockIdx.y * 64;
  const int t = threadIdx.x;
  const int r0 = t >> 4;         // 0..15
  const int c0 = (t & 15) * 4;   // 0..60
#pragma unroll
  for (int ii = 0; ii < 4; ++ii) {
    int r = ii * 16 + r0;
    float4 v = *reinterpret_cast<const float4*>(&in[(size_t)(tR + r) * Cc + tC + c0]);
    tile[r][c0] = v.x; tile[r][c0 + 1] = v.y; tile[r][c0 + 2] = v.z; tile[r][c0 + 3] = v.w;
  }
  __syncthreads();
#pragma unroll
  for (int ii = 0; ii < 4; ++ii) {
    int c = ii * 16 + r0;  // output row (= input col)
    ushort4 o;
    o.x = f2b(tile[c0 + 0][c]);
    o.y = f2b(tile[c0 + 1][c]);
    o.z = f2b(tile[c0 + 2][c]);
    o.w = f2b(tile[c0 + 3][c]);
    *reinterpret_cast<ushort4*>(&out[(size_t)(tC + c) * R + tR + c0]) = o;
  }
}

// ---------------- per-tile (64q x 64k) mask nonzero flags ----------------
// bid = b*1024 + qs*32 + kt
__global__ void k_maskflags(const float* __restrict__ mask, u32* __restrict__ flags) {
  const int bid = blockIdx.x;
  const int kt = bid & 31, qs = (bid >> 5) & 31, b = bid >> 10;
  const int t = threadIdx.x;
  const float* base = mask + ((size_t)b * C_ + qs * 64) * C_ + kt * 64;
  const int row = t >> 2, c0 = (t & 3) * 16;
  int any = 0;
#pragma unroll
  for (int i = 0; i < 4; ++i) {
    float4 v = *reinterpret_cast<const float4*>(base + (size_t)row * C_ + c0 + i * 4);
    any |= (v.x != 0.f) | (v.y != 0.f) | (v.z != 0.f) | (v.w != 0.f);
  }
  __shared__ int sh[4];
  const unsigned long long bal = __ballot(any);
  if ((t & 63) == 0) sh[t >> 6] = (bal != 0ull);
  __syncthreads();
  if (t == 0) flags[bid] = (u32)(sh[0] | sh[1] | sh[2] | sh[3]);
}

// ---------------- async global->LDS, 16B per lane ----------------
#define GLL16(gptr, lptr) __builtin_amdgcn_global_load_lds( \
    (const __attribute__((address_space(1))) u32*)(gptr),   \
    (__attribute__((address_space(3))) u32*)(lptr), 16, 0, 0)

// ---------------- BMx128 bf16 GEMM (BK=64, swizzled LDS), C = A * Bt^T + bias ----
// EPI 0: scatter Q/K -> [B,H,C,hd], V -> transposed [B,H,hd,C].  EPI 1: f32 C + bias.
template<int EPI, int BM>
__global__ __launch_bounds__(256) void k_gemm(
    const u16* __restrict__ A, const u16* __restrict__ Bt,
    int M, int N, int K, const float* __restrict__ bias,
    u16* __restrict__ Cq, u16* __restrict__ Ck, u16* __restrict__ Cv,
    float* __restrict__ Cf)
{
  constexpr int WCW = (BM == 128) ? 64 : 32;   // per-wave col width
  constexpr int NF = WCW / 16;                 // n-frags per wave
  __shared__ __align__(16) u16 As[BM * 64];
  __shared__ __align__(16) u16 Bs[128 * 64];
  const int t = threadIdx.x;
  const int l = t & 63, w = t >> 6;
  const int wr = (BM == 128) ? (w >> 1) : 0;
  const int wc = (BM == 128) ? (w & 1) : w;
  const int lr = l & 15, lg = l >> 4;
  const int swk = lr & 7;
  const int m0 = blockIdx.y * BM, n0 = blockIdx.x * 128;
  f32x4 acc[4][NF] = {};

  for (int k0 = 0; k0 < K; k0 += 64) {
#pragma unroll
    for (int s = 0; s < BM / 32; ++s) {        // A: BM*8 16B-units
      const int u = s * 256 + t;
      const int row = u >> 3, slot = (u & 7) ^ (row & 7);
      GLL16(A + (size_t)(m0 + row) * K + k0 + (slot << 3), As + (u << 3));
    }
#pragma unroll
    for (int s = 0; s < 4; ++s) {              // B: 1024 16B-units
      const int u = s * 256 + t;
      const int row = u >> 3, slot = (u & 7) ^ (row & 7);
      GLL16(Bt + (size_t)(n0 + row) * K + k0 + (slot << 3), Bs + (u << 3));
    }
    __syncthreads();
    short8 af[2][4], bfr[2][NF];
#pragma unroll
    for (int s = 0; s < 2; ++s) {
#pragma unroll
      for (int m = 0; m < 4; ++m)
        af[s][m] = *reinterpret_cast<const short8*>(
            &As[((wr * 64 + m * 16 + lr) << 6) + (((s * 4 + lg) ^ swk) << 3)]);
#pragma unroll
      for (int n = 0; n < NF; ++n)
        bfr[s][n] = *reinterpret_cast<const short8*>(
            &Bs[((wc * WCW + n * 16 + lr) << 6) + (((s * 4 + lg) ^ swk) << 3)]);
    }
#pragma unroll
    for (int s = 0; s < 2; ++s)
#pragma unroll
      for (int m = 0; m < 4; ++m)
#pragma unroll
        for (int n = 0; n < NF; ++n)
          acc[m][n] = __builtin_amdgcn_mfma_f32_16x16x32_bf16(af[s][m], bfr[s][n], acc[m][n], 0, 0, 0);
    __syncthreads();
  }

#pragma unroll
  for (int m = 0; m < 4; ++m) {
    const int mg = m0 + wr * 64 + m * 16 + lg * 4;
    const int bq = mg >> 11, c0 = mg & 2047;
#pragma unroll
    for (int n = 0; n < NF; ++n) {
      const int ng = n0 + wc * WCW + n * 16 + lr;
      const float bia = bias[ng];
      if (EPI == 0) {
        const int reg = ng >> 10, d = ng & 1023, h = d >> 6, e = d & 63;
        if (reg == 2) {
          u16* vp = Cv + (((size_t)(bq * H_ + h) * HD_ + e) << 11) + c0;  // [B,H,hd,C]
#pragma unroll
          for (int j = 0; j < 4; ++j) vp[j] = f2b(acc[m][n][j] + bia);
        } else {
          u16* dst = (reg == 0) ? Cq : Ck;
#pragma unroll
          for (int j = 0; j < 4; ++j)
            dst[(((size_t)(bq * H_ + h) * C_ + c0 + j) << 6) + e] = f2b(acc[m][n][j] + bia);
        }
      } else {
#pragma unroll
        for (int j = 0; j < 4; ++j)
          Cf[(size_t)(mg + j) * N + ng] = acc[m][n][j] + bia;
      }
    }
  }
}

// stage one K tile [64 keys][64 hd] and one Vt tile [64 hd][64 keys] via DMA.
// LDS linear dest; source 16B-slot pre-XOR-swizzled (T21): slot ^= row&7.
static __device__ __forceinline__ void stage_kv(
    const u16* __restrict__ Kbh, const u16* __restrict__ Vbh,
    u16* Kd, u16* Vd, int kt, int t)
{
#pragma unroll
  for (int ch = 0; ch < 2; ++ch) {
    const int u = ch * 256 + t;
    const int row = u >> 3, slot = (u & 7) ^ (row & 7);
    GLL16(Kbh + (((size_t)(kt * 64 + row)) << 6) + (slot << 3), Kd + (u << 3));
    GLL16(Vbh + (((size_t)row) << 11) + kt * 64 + (slot << 3), Vd + (u << 3));
  }
}

// ---------------- causal flash attention (v5.1: swapped-operand 32x32) ------------
// grid: 256 = 8 pairs x 32 bh; block covers q-tiles {pr,15-pr} of 128 rows (2 phases).
// 4 warps x 32 q-rows each; KVBLK=64. QK^T computed as mfma(K,Q) -> D[key][q]:
// each lane owns q=lane&31; softmax fully in-lane + one shfl_xor(32).
// PV computed as mfma(Vt,P) -> O^T[d][q]: rescale is per-lane uniform.
// v5.1: __syncthreads (fence!) instead of raw s_barrier; mn floored at -1e30;
//       compiler mem-barriers around same-wave LDS write->read pairs.
__global__ __launch_bounds__(256) void k_attn(
    const u16* __restrict__ Q, const u16* __restrict__ Kb, const u16* __restrict__ Vt,
    const float* __restrict__ mask, const u32* __restrict__ flags, u16* __restrict__ O)
{
  __shared__ __align__(16) u16 Kl[2][64 * 64];
  __shared__ __align__(16) u16 Vl[2][64 * 64];
  __shared__ __align__(16) u16 Sc[4][2304];   // per-warp: P [32][64] (4KB) / Ol 32x144B
  const int bid = blockIdx.x;
  const int bh = bid & 31;                    // bid%8 == bh%8 -> XCD-local K/V
  const int pr = bid >> 5;                    // 0..7
  const int b = bh >> 4, h = bh & 15;
  const int t = threadIdx.x;
  const int l = t & 63, w = t >> 6;
  const int q = l & 31, hi = l >> 5;
  const int q7 = q & 7;

  const u16* Kbh = Kb + (size_t)bh * (C_ * HD_);
  const u16* Vbh = Vt + (size_t)bh * (HD_ * C_);
  char* Swb = reinterpret_cast<char*>(Sc[w]);

#pragma unroll 1
  for (int phase = 0; phase < 2; ++phase) {
    const int qt = phase ? (15 - pr) : pr;
    const int ktb = 2 * qt + 2;
    const int q0w = qt * 128 + w * 32;
    const int qg = q0w + q;
    const int qmaxw = q0w + 31;

    // Q frags (B-operand: lane q=lane&31, k-slice=8*hi+i), pre-scaled by hd^-0.5
    short8 aq[4];
    {
      const u16* qp = Q + ((size_t)bh * C_ + qg) * HD_ + hi * 8;
#pragma unroll
      for (int kh = 0; kh < 4; ++kh) {
        short8 v = *reinterpret_cast<const short8*>(qp + kh * 16);
#pragma unroll
        for (int i = 0; i < 8; ++i) {
          const float f = __builtin_bit_cast(float, (u32)((u16)v[i]) << 16) * 0.125f;
          v[i] = (short)f2b(f);
        }
        aq[kh] = v;
      }
    }

    f32x16 oa0 = {}, oa1 = {};
    float mrun = -INFINITY, srun = 0.f;
    const float* mrow = mask + ((size_t)b * C_ + qg) * C_;
    const u32* fb = flags + (size_t)(b * 32 + (q0w >> 6)) * 32;

    stage_kv(Kbh, Vbh, Kl[0], Vl[0], 0, t);

#pragma unroll 1
    for (int kt = 0; kt < ktb; ++kt) {
      const int cur = kt & 1;
      __syncthreads();                        // drains own vmcnt + fence + barrier
      if (kt + 1 < ktb) stage_kv(Kbh, Vbh, Kl[cur ^ 1], Vl[cur ^ 1], kt + 1, t);
      if (kt * 64 > qmaxw) continue;          // warp fully past-causal for this tile

      const char* Kc = reinterpret_cast<const char*>(Kl[cur]);
      const char* Vc = reinterpret_cast<const char*>(Vl[cur]);

      // S^T = K Q^T : D[key][q]; p0 = keys kt*64+[0,32), p1 = +[32,64)
      f32x16 p0 = {}, p1 = {};
#pragma unroll
      for (int kh = 0; kh < 4; ++kh) {
        const int sl = ((2 * kh + hi) ^ q7) << 4;
        const short8 k0 = *reinterpret_cast<const short8*>(Kc + q * 128 + sl);
        const short8 k1 = *reinterpret_cast<const short8*>(Kc + (32 + q) * 128 + sl);
        p0 = __builtin_amdgcn_mfma_f32_32x32x16_bf16(k0, aq[kh], p0, 0, 0, 0);
        p1 = __builtin_amdgcn_mfma_f32_32x32x16_bf16(k1, aq[kh], p1, 0, 0, 0);
      }

      // additive mask (only when tile nonzero)
      if (fb[kt]) {
        const float* mp = mrow + kt * 64 + 4 * hi;
#pragma unroll
        for (int g = 0; g < 4; ++g) {
          const float4 m0 = *reinterpret_cast<const float4*>(mp + 8 * g);
          const float4 m1 = *reinterpret_cast<const float4*>(mp + 32 + 8 * g);
          p0[4*g+0] += m0.x; p0[4*g+1] += m0.y; p0[4*g+2] += m0.z; p0[4*g+3] += m0.w;
          p1[4*g+0] += m1.x; p1[4*g+1] += m1.y; p1[4*g+2] += m1.z; p1[4*g+3] += m1.w;
        }
      }
      // causal clamp (diagonal region only)
      if (kt * 64 + 63 > q0w) {
#pragma unroll
        for (int r = 0; r < 16; ++r) {
          const int kl = kt * 64 + (r & 3) + 8 * (r >> 2) + 4 * hi;
          if (kl > qg) p0[r] = -INFINITY;
          if (kl + 32 > qg) p1[r] = -INFINITY;
        }
      }

      // online softmax: in-lane over 32 scores + one cross-half shfl.
      // mn floored at -1e30 so exp args are always well-defined (no inf-inf).
      float pm = -INFINITY;
#pragma unroll
      for (int r = 0; r < 16; ++r) pm = fmaxf(pm, fmaxf(p0[r], p1[r]));
      pm = fmaxf(pm, __shfl_xor(pm, 32));
      const float mn = fmaxf(fmaxf(mrun, pm), -1e30f);
      const float rs = __expf(mrun - mn);     // first iter: exp(-inf)=0
      float sum = 0.f;
#pragma unroll
      for (int r = 0; r < 16; ++r) {
        p0[r] = __expf(p0[r] - mn); sum += p0[r];
        p1[r] = __expf(p1[r] - mn); sum += p1[r];
      }
      sum += __shfl_xor(sum, 32);
      srun = srun * rs + sum;
      mrun = mn;
      oa0 *= rs; oa1 *= rs;

      // P -> per-warp LDS [32 q][64 keys], 16B-slot swizzled by q&7
#pragma unroll
      for (int g = 0; g < 4; ++g) {
#pragma unroll
        for (int m = 0; m < 2; ++m) {
          u32 w0, w1;
          asm("v_cvt_pk_bf16_f32 %0, %1, %2" : "=v"(w0) : "v"(p0[4*g+2*m]), "v"(p0[4*g+2*m+1]));
          asm("v_cvt_pk_bf16_f32 %0, %1, %2" : "=v"(w1) : "v"(p1[4*g+2*m]), "v"(p1[4*g+2*m+1]));
          *reinterpret_cast<u32*>(Swb + q * 128 + ((g ^ q7) << 4) + 8 * hi + 4 * m) = w0;
          *reinterpret_cast<u32*>(Swb + q * 128 + (((4 + g) ^ q7) << 4) + 8 * hi + 4 * m) = w1;
        }
      }
      asm volatile("" ::: "memory");          // order same-wave LDS write -> read

      // O^T += Vt x P : D[d][q]
#pragma unroll
      for (int ks = 0; ks < 4; ++ks) {
        const int sl = ((2 * ks + hi) ^ q7) << 4;
        const short8 bp = *reinterpret_cast<const short8*>(Swb + q * 128 + sl);
        const short8 v0 = *reinterpret_cast<const short8*>(Vc + q * 128 + sl);
        const short8 v1 = *reinterpret_cast<const short8*>(Vc + (32 + q) * 128 + sl);
        oa0 = __builtin_amdgcn_mfma_f32_32x32x16_bf16(v0, bp, oa0, 0, 0, 0);
        oa1 = __builtin_amdgcn_mfma_f32_32x32x16_bf16(v1, bp, oa1, 0, 0, 0);
      }
    }

    // epilogue: normalize, transpose via per-warp LDS (rows 144B), vector store
    const float rinv = 1.f / srun;
#pragma unroll
    for (int g = 0; g < 4; ++g) {
      const int d0 = 8 * g + 4 * hi;
      const float a0 = oa0[4*g+0] * rinv, a1 = oa0[4*g+1] * rinv;
      const float a2 = oa0[4*g+2] * rinv, a3 = oa0[4*g+3] * rinv;
      const float b0 = oa1[4*g+0] * rinv, b1 = oa1[4*g+1] * rinv;
      const float b2 = oa1[4*g+2] * rinv, b3 = oa1[4*g+3] * rinv;
      u32 w0, w1, w2, w3;
      asm("v_cvt_pk_bf16_f32 %0, %1, %2" : "=v"(w0) : "v"(a0), "v"(a1));
      asm("v_cvt_pk_bf16_f32 %0, %1, %2" : "=v"(w1) : "v"(a2), "v"(a3));
      asm("v_cvt_pk_bf16_f32 %0, %1, %2" : "=v"(w2) : "v"(b0), "v"(b1));
      asm("v_cvt_pk_bf16_f32 %0, %1, %2" : "=v"(w3) : "v"(b2), "v"(b3));
      *reinterpret_cast<uint2*>(Swb + q * 144 + d0 * 2) = make_uint2(w0, w1);
      *reinterpret_cast<uint2*>(Swb + q * 144 + (d0 + 32) * 2) = make_uint2(w2, w3);
    }
    asm volatile("" ::: "memory");            // order same-wave LDS write -> read
    const int q2 = l >> 1, hf = l & 1;
    u16* orow = O + ((size_t)b * C_ + q0w + q2) * D_ + h * 64 + hf * 32;
#pragma unroll
    for (int i = 0; i < 4; ++i) {
      const short8 v = *reinterpret_cast<const short8*>(Swb + q2 * 144 + hf * 64 + i * 16);
      *reinterpret_cast<short8*>(orow + i * 8) = v;
    }
  }
}

extern "C" void kernel_launch(void* const* d_in, const int* in_sizes, int n_in,
                              void* d_out, int out_size, void* d_ws, size_t ws_size,
                              hipStream_t stream) {
  const float* hs   = (const float*)d_in[0];
  const float* mask = (const float*)d_in[1];
  const float* Wqkv = (const float*)d_in[2];
  const float* bqkv = (const float*)d_in[3];
  const float* Wo   = (const float*)d_in[4];
  const float* bo   = (const float*)d_in[5];
  float* out = (float*)d_out;
  char* ws = (char*)d_ws;

  u16* hsb   = (u16*)(ws);                 // 8 MB [4096][1024]
  u16* Wqkvt = (u16*)(ws + (8  << 20));    // 6 MB [3072][1024]
  u16* Wot   = (u16*)(ws + (14 << 20));    // 2 MB [1024][1024]
  u16* Qb    = (u16*)(ws + (16 << 20));    // 8 MB [2,16,2048,64]
  u16* Kb    = (u16*)(ws + (24 << 20));    // 8 MB [2,16,2048,64]
  u32* flags = (u32*)(ws + (32 << 20));    // 8 KB [2][32][32]
  u16* Vtb   = (u16*)(ws + (40 << 20));    // 8 MB [2,16,64,2048]
  u16* AOb   = (u16*)(ws + (48 << 20));    // 8 MB [4096][1024]

  k_convert<<<2048, 256, 0, stream>>>(hs, hsb, 4096 * 1024);
  k_tconv<<<dim3(3072 / 64, 1024 / 64), 256, 0, stream>>>(Wqkv, Wqkvt, 1024, 3072);
  k_tconv<<<dim3(1024 / 64, 1024 / 64), 256, 0, stream>>>(Wo, Wot, 1024, 1024);
  k_maskflags<<<2048, 256, 0, stream>>>(mask, flags);
  k_gemm<0, 128><<<dim3(24, 32), 256, 0, stream>>>(hsb, Wqkvt, 4096, 3072, 1024, bqkv,
                                                   Qb, Kb, Vtb, nullptr);
  k_attn<<<256, 256, 0, stream>>>(Qb, Kb, Vtb, mask, flags, AOb);
  k_gemm<1, 64><<<dim3(8, 64), 256, 0, stream>>>(AOb, Wot, 4096, 1024, 1024, bo,
                                                 nullptr, nullptr, nullptr, out);
}

// Round 7
// 137.173 us; speedup vs baseline: 1.7656x; 1.0040x over previous
//
#include <hip/hip_runtime.h>
#include <hip/hip_bf16.h>
#include <cstdint>
#include <cstddef>

typedef __attribute__((ext_vector_type(8))) short short8;
typedef __attribute__((ext_vector_type(4))) float f32x4;
typedef __attribute__((ext_vector_type(16))) float f32x16;
typedef unsigned short u16;
typedef unsigned int u32;

#define B_ 2
#define C_ 2048
#define D_ 1024
#define H_ 16
#define HD_ 64

static __device__ __forceinline__ u16 f2b(float f) {
  u32 x = __builtin_bit_cast(u32, f);
  x += 0x7FFFu + ((x >> 16) & 1u);
  return (u16)(x >> 16);
}

// ---------------- plain convert f32 -> bf16 ----------------
__global__ void k_convert(const float* __restrict__ in, u16* __restrict__ out, int n) {
  int i = (blockIdx.x * blockDim.x + threadIdx.x) * 4;
  const int stride = gridDim.x * blockDim.x * 4;
  for (; i < n; i += stride) {
    float4 v = *reinterpret_cast<const float4*>(in + i);
    ushort4 o;
    o.x = f2b(v.x); o.y = f2b(v.y); o.z = f2b(v.z); o.w = f2b(v.w);
    *reinterpret_cast<ushort4*>(out + i) = o;
  }
}

// ---------------- transpose + convert: in[R][Cc] f32 -> out[Cc][R] bf16 ----------------
__global__ void k_tconv(const float* __restrict__ in, u16* __restrict__ out, int R, int Cc) {
  __shared__ float tile[64][65];
  const int tC = blockIdx.x * 64;
  const int tR = blockIdx.y * 64;
  const int t = threadIdx.x;
  const int r0 = t >> 4;         // 0..15
  const int c0 = (t & 15) * 4;   // 0..60
#pragma unroll
  for (int ii = 0; ii < 4; ++ii) {
    int r = ii * 16 + r0;
    float4 v = *reinterpret_cast<const float4*>(&in[(size_t)(tR + r) * Cc + tC + c0]);
    tile[r][c0] = v.x; tile[r][c0 + 1] = v.y; tile[r][c0 + 2] = v.z; tile[r][c0 + 3] = v.w;
  }
  __syncthreads();
#pragma unroll
  for (int ii = 0; ii < 4; ++ii) {
    int c = ii * 16 + r0;  // output row (= input col)
    ushort4 o;
    o.x = f2b(tile[c0 + 0][c]);
    o.y = f2b(tile[c0 + 1][c]);
    o.z = f2b(tile[c0 + 2][c]);
    o.w = f2b(tile[c0 + 3][c]);
    *reinterpret_cast<ushort4*>(&out[(size_t)(tC + c) * R + tR + c0]) = o;
  }
}

// ---------------- per-tile (64q x 64k) mask nonzero flags ----------------
// bid = b*1024 + qs*32 + kt
__global__ void k_maskflags(const float* __restrict__ mask, u32* __restrict__ flags) {
  const int bid = blockIdx.x;
  const int kt = bid & 31, qs = (bid >> 5) & 31, b = bid >> 10;
  const int t = threadIdx.x;
  const float* base = mask + ((size_t)b * C_ + qs * 64) * C_ + kt * 64;
  const int row = t >> 2, c0 = (t & 3) * 16;
  int any = 0;
#pragma unroll
  for (int i = 0; i < 4; ++i) {
    float4 v = *reinterpret_cast<const float4*>(base + (size_t)row * C_ + c0 + i * 4);
    any |= (v.x != 0.f) | (v.y != 0.f) | (v.z != 0.f) | (v.w != 0.f);
  }
  __shared__ int sh[4];
  const unsigned long long bal = __ballot(any);
  if ((t & 63) == 0) sh[t >> 6] = (bal != 0ull);
  __syncthreads();
  if (t == 0) flags[bid] = (u32)(sh[0] | sh[1] | sh[2] | sh[3]);
}

// ---------------- async global->LDS, 16B per lane ----------------
#define GLL16(gptr, lptr) __builtin_amdgcn_global_load_lds( \
    (const __attribute__((address_space(1))) u32*)(gptr),   \
    (__attribute__((address_space(3))) u32*)(lptr), 16, 0, 0)

// ---------------- BMx128 bf16 GEMM (BK=64, swizzled LDS), C = A * Bt^T + bias ----
// EPI 0: scatter Q/K -> [B,H,C,hd], V -> transposed [B,H,hd,C].  EPI 1: f32 C + bias.
template<int EPI, int BM>
__global__ __launch_bounds__(256) void k_gemm(
    const u16* __restrict__ A, const u16* __restrict__ Bt,
    int M, int N, int K, const float* __restrict__ bias,
    u16* __restrict__ Cq, u16* __restrict__ Ck, u16* __restrict__ Cv,
    float* __restrict__ Cf)
{
  constexpr int WCW = (BM == 128) ? 64 : 32;   // per-wave col width
  constexpr int NF = WCW / 16;                 // n-frags per wave
  __shared__ __align__(16) u16 As[BM * 64];
  __shared__ __align__(16) u16 Bs[128 * 64];
  const int t = threadIdx.x;
  const int l = t & 63, w = t >> 6;
  const int wr = (BM == 128) ? (w >> 1) : 0;
  const int wc = (BM == 128) ? (w & 1) : w;
  const int lr = l & 15, lg = l >> 4;
  const int swk = lr & 7;
  const int m0 = blockIdx.y * BM, n0 = blockIdx.x * 128;
  f32x4 acc[4][NF] = {};

  for (int k0 = 0; k0 < K; k0 += 64) {
#pragma unroll
    for (int s = 0; s < BM / 32; ++s) {        // A: BM*8 16B-units
      const int u = s * 256 + t;
      const int row = u >> 3, slot = (u & 7) ^ (row & 7);
      GLL16(A + (size_t)(m0 + row) * K + k0 + (slot << 3), As + (u << 3));
    }
#pragma unroll
    for (int s = 0; s < 4; ++s) {              // B: 1024 16B-units
      const int u = s * 256 + t;
      const int row = u >> 3, slot = (u & 7) ^ (row & 7);
      GLL16(Bt + (size_t)(n0 + row) * K + k0 + (slot << 3), Bs + (u << 3));
    }
    __syncthreads();
    short8 af[2][4], bfr[2][NF];
#pragma unroll
    for (int s = 0; s < 2; ++s) {
#pragma unroll
      for (int m = 0; m < 4; ++m)
        af[s][m] = *reinterpret_cast<const short8*>(
            &As[((wr * 64 + m * 16 + lr) << 6) + (((s * 4 + lg) ^ swk) << 3)]);
#pragma unroll
      for (int n = 0; n < NF; ++n)
        bfr[s][n] = *reinterpret_cast<const short8*>(
            &Bs[((wc * WCW + n * 16 + lr) << 6) + (((s * 4 + lg) ^ swk) << 3)]);
    }
#pragma unroll
    for (int s = 0; s < 2; ++s)
#pragma unroll
      for (int m = 0; m < 4; ++m)
#pragma unroll
        for (int n = 0; n < NF; ++n)
          acc[m][n] = __builtin_amdgcn_mfma_f32_16x16x32_bf16(af[s][m], bfr[s][n], acc[m][n], 0, 0, 0);
    __syncthreads();
  }

#pragma unroll
  for (int m = 0; m < 4; ++m) {
    const int mg = m0 + wr * 64 + m * 16 + lg * 4;
    const int bq = mg >> 11, c0 = mg & 2047;
#pragma unroll
    for (int n = 0; n < NF; ++n) {
      const int ng = n0 + wc * WCW + n * 16 + lr;
      const float bia = bias[ng];
      if (EPI == 0) {
        const int reg = ng >> 10, d = ng & 1023, h = d >> 6, e = d & 63;
        if (reg == 2) {
          u16* vp = Cv + (((size_t)(bq * H_ + h) * HD_ + e) << 11) + c0;  // [B,H,hd,C]
#pragma unroll
          for (int j = 0; j < 4; ++j) vp[j] = f2b(acc[m][n][j] + bia);
        } else {
          u16* dst = (reg == 0) ? Cq : Ck;
#pragma unroll
          for (int j = 0; j < 4; ++j)
            dst[(((size_t)(bq * H_ + h) * C_ + c0 + j) << 6) + e] = f2b(acc[m][n][j] + bia);
        }
      } else {
#pragma unroll
        for (int j = 0; j < 4; ++j)
          Cf[(size_t)(mg + j) * N + ng] = acc[m][n][j] + bia;
      }
    }
  }
}

// stage one K tile [64 keys][64 hd] and one Vt tile [64 hd][64 keys] via DMA.
// LDS linear dest; source 16B-slot pre-XOR-swizzled (T21): slot ^= row&7.
static __device__ __forceinline__ void stage_kv(
    const u16* __restrict__ Kbh, const u16* __restrict__ Vbh,
    u16* Kd, u16* Vd, int kt, int t)
{
#pragma unroll
  for (int ch = 0; ch < 2; ++ch) {
    const int u = ch * 256 + t;
    const int row = u >> 3, slot = (u & 7) ^ (row & 7);
    GLL16(Kbh + (((size_t)(kt * 64 + row)) << 6) + (slot << 3), Kd + (u << 3));
    GLL16(Vbh + (((size_t)row) << 11) + kt * 64 + (slot << 3), Vd + (u << 3));
  }
}

// ---------------- causal flash attention (v6: unpaired, grid 512) ------------
// grid: 512 = 16 q-tiles (big-first) x 32 bh; block = one 128-row q-tile.
// 4 warps x 32 q-rows each; KVBLK=64. QK^T computed as mfma(K,Q) -> D[key][q]:
// each lane owns q=lane&31; softmax fully in-lane + one shfl_xor(32).
// PV computed as mfma(Vt,P) -> O^T[d][q]: rescale is per-lane uniform.
// Big-first dispatch = LPT scheduling; 2 blocks/CU co-resident hide barrier/DMA stalls.
__global__ __launch_bounds__(256) void k_attn(
    const u16* __restrict__ Q, const u16* __restrict__ Kb, const u16* __restrict__ Vt,
    const float* __restrict__ mask, const u32* __restrict__ flags, u16* __restrict__ O)
{
  __shared__ __align__(16) u16 Kl[2][64 * 64];
  __shared__ __align__(16) u16 Vl[2][64 * 64];
  __shared__ __align__(16) u16 Sc[4][2304];   // per-warp: P [32][64] (4KB) / Ol 32x144B
  const int bid = blockIdx.x;
  const int bh = bid & 31;                    // bid%8 == bh%8 -> XCD-local K/V
  const int qt = 15 - (bid >> 5);             // big tiles dispatch first (LPT)
  const int b = bh >> 4, h = bh & 15;
  const int t = threadIdx.x;
  const int l = t & 63, w = t >> 6;
  const int q = l & 31, hi = l >> 5;
  const int q7 = q & 7;

  const u16* Kbh = Kb + (size_t)bh * (C_ * HD_);
  const u16* Vbh = Vt + (size_t)bh * (HD_ * C_);
  char* Swb = reinterpret_cast<char*>(Sc[w]);

  const int ktb = 2 * qt + 2;
  const int q0w = qt * 128 + w * 32;
  const int qg = q0w + q;
  const int qmaxw = q0w + 31;

  // Q frags (B-operand: lane q=lane&31, k-slice=8*hi+i), pre-scaled by hd^-0.5
  short8 aq[4];
  {
    const u16* qp = Q + ((size_t)bh * C_ + qg) * HD_ + hi * 8;
#pragma unroll
    for (int kh = 0; kh < 4; ++kh) {
      short8 v = *reinterpret_cast<const short8*>(qp + kh * 16);
#pragma unroll
      for (int i = 0; i < 8; ++i) {
        const float f = __builtin_bit_cast(float, (u32)((u16)v[i]) << 16) * 0.125f;
        v[i] = (short)f2b(f);
      }
      aq[kh] = v;
    }
  }

  f32x16 oa0 = {}, oa1 = {};
  float mrun = -INFINITY, srun = 0.f;
  const float* mrow = mask + ((size_t)b * C_ + qg) * C_;
  const u32* fb = flags + (size_t)(b * 32 + (q0w >> 6)) * 32;

  stage_kv(Kbh, Vbh, Kl[0], Vl[0], 0, t);

#pragma unroll 1
  for (int kt = 0; kt < ktb; ++kt) {
    const int cur = kt & 1;
    __syncthreads();                        // drains own vmcnt + fence + barrier
    if (kt + 1 < ktb) stage_kv(Kbh, Vbh, Kl[cur ^ 1], Vl[cur ^ 1], kt + 1, t);
    if (kt * 64 > qmaxw) continue;          // warp fully past-causal for this tile

    const char* Kc = reinterpret_cast<const char*>(Kl[cur]);
    const char* Vc = reinterpret_cast<const char*>(Vl[cur]);

    // S^T = K Q^T : D[key][q]; p0 = keys kt*64+[0,32), p1 = +[32,64)
    f32x16 p0 = {}, p1 = {};
#pragma unroll
    for (int kh = 0; kh < 4; ++kh) {
      const int sl = ((2 * kh + hi) ^ q7) << 4;
      const short8 k0 = *reinterpret_cast<const short8*>(Kc + q * 128 + sl);
      const short8 k1 = *reinterpret_cast<const short8*>(Kc + (32 + q) * 128 + sl);
      p0 = __builtin_amdgcn_mfma_f32_32x32x16_bf16(k0, aq[kh], p0, 0, 0, 0);
      p1 = __builtin_amdgcn_mfma_f32_32x32x16_bf16(k1, aq[kh], p1, 0, 0, 0);
    }

    // additive mask (only when tile nonzero)
    if (fb[kt]) {
      const float* mp = mrow + kt * 64 + 4 * hi;
#pragma unroll
      for (int g = 0; g < 4; ++g) {
        const float4 m0 = *reinterpret_cast<const float4*>(mp + 8 * g);
        const float4 m1 = *reinterpret_cast<const float4*>(mp + 32 + 8 * g);
        p0[4*g+0] += m0.x; p0[4*g+1] += m0.y; p0[4*g+2] += m0.z; p0[4*g+3] += m0.w;
        p1[4*g+0] += m1.x; p1[4*g+1] += m1.y; p1[4*g+2] += m1.z; p1[4*g+3] += m1.w;
      }
    }
    // causal clamp (diagonal region only)
    if (kt * 64 + 63 > q0w) {
#pragma unroll
      for (int r = 0; r < 16; ++r) {
        const int kl = kt * 64 + (r & 3) + 8 * (r >> 2) + 4 * hi;
        if (kl > qg) p0[r] = -INFINITY;
        if (kl + 32 > qg) p1[r] = -INFINITY;
      }
    }

    // online softmax: in-lane over 32 scores + one cross-half shfl.
    // mn floored at -1e30 so exp args are always well-defined (no inf-inf).
    float pm = -INFINITY;
#pragma unroll
    for (int r = 0; r < 16; ++r) pm = fmaxf(pm, fmaxf(p0[r], p1[r]));
    pm = fmaxf(pm, __shfl_xor(pm, 32));
    const float mn = fmaxf(fmaxf(mrun, pm), -1e30f);
    const float rs = __expf(mrun - mn);     // first iter: exp(-inf)=0
    float sum = 0.f;
#pragma unroll
    for (int r = 0; r < 16; ++r) {
      p0[r] = __expf(p0[r] - mn); sum += p0[r];
      p1[r] = __expf(p1[r] - mn); sum += p1[r];
    }
    sum += __shfl_xor(sum, 32);
    srun = srun * rs + sum;
    mrun = mn;
    oa0 *= rs; oa1 *= rs;

    // P -> per-warp LDS [32 q][64 keys], 16B-slot swizzled by q&7
#pragma unroll
    for (int g = 0; g < 4; ++g) {
#pragma unroll
      for (int m = 0; m < 2; ++m) {
        u32 w0, w1;
        asm("v_cvt_pk_bf16_f32 %0, %1, %2" : "=v"(w0) : "v"(p0[4*g+2*m]), "v"(p0[4*g+2*m+1]));
        asm("v_cvt_pk_bf16_f32 %0, %1, %2" : "=v"(w1) : "v"(p1[4*g+2*m]), "v"(p1[4*g+2*m+1]));
        *reinterpret_cast<u32*>(Swb + q * 128 + ((g ^ q7) << 4) + 8 * hi + 4 * m) = w0;
        *reinterpret_cast<u32*>(Swb + q * 128 + (((4 + g) ^ q7) << 4) + 8 * hi + 4 * m) = w1;
      }
    }
    asm volatile("" ::: "memory");          // order same-wave LDS write -> read

    // O^T += Vt x P : D[d][q]
#pragma unroll
    for (int ks = 0; ks < 4; ++ks) {
      const int sl = ((2 * ks + hi) ^ q7) << 4;
      const short8 bp = *reinterpret_cast<const short8*>(Swb + q * 128 + sl);
      const short8 v0 = *reinterpret_cast<const short8*>(Vc + q * 128 + sl);
      const short8 v1 = *reinterpret_cast<const short8*>(Vc + (32 + q) * 128 + sl);
      oa0 = __builtin_amdgcn_mfma_f32_32x32x16_bf16(v0, bp, oa0, 0, 0, 0);
      oa1 = __builtin_amdgcn_mfma_f32_32x32x16_bf16(v1, bp, oa1, 0, 0, 0);
    }
  }

  // epilogue: normalize, transpose via per-warp LDS (rows 144B), vector store
  const float rinv = 1.f / srun;
#pragma unroll
  for (int g = 0; g < 4; ++g) {
    const int d0 = 8 * g + 4 * hi;
    const float a0 = oa0[4*g+0] * rinv, a1 = oa0[4*g+1] * rinv;
    const float a2 = oa0[4*g+2] * rinv, a3 = oa0[4*g+3] * rinv;
    const float b0 = oa1[4*g+0] * rinv, b1 = oa1[4*g+1] * rinv;
    const float b2 = oa1[4*g+2] * rinv, b3 = oa1[4*g+3] * rinv;
    u32 w0, w1, w2, w3;
    asm("v_cvt_pk_bf16_f32 %0, %1, %2" : "=v"(w0) : "v"(a0), "v"(a1));
    asm("v_cvt_pk_bf16_f32 %0, %1, %2" : "=v"(w1) : "v"(a2), "v"(a3));
    asm("v_cvt_pk_bf16_f32 %0, %1, %2" : "=v"(w2) : "v"(b0), "v"(b1));
    asm("v_cvt_pk_bf16_f32 %0, %1, %2" : "=v"(w3) : "v"(b2), "v"(b3));
    *reinterpret_cast<uint2*>(Swb + q * 144 + d0 * 2) = make_uint2(w0, w1);
    *reinterpret_cast<uint2*>(Swb + q * 144 + (d0 + 32) * 2) = make_uint2(w2, w3);
  }
  asm volatile("" ::: "memory");            // order same-wave LDS write -> read
  const int q2 = l >> 1, hf = l & 1;
  u16* orow = O + ((size_t)b * C_ + q0w + q2) * D_ + h * 64 + hf * 32;
#pragma unroll
  for (int i = 0; i < 4; ++i) {
    const short8 v = *reinterpret_cast<const short8*>(Swb + q2 * 144 + hf * 64 + i * 16);
    *reinterpret_cast<short8*>(orow + i * 8) = v;
  }
}

extern "C" void kernel_launch(void* const* d_in, const int* in_sizes, int n_in,
                              void* d_out, int out_size, void* d_ws, size_t ws_size,
                              hipStream_t stream) {
  const float* hs   = (const float*)d_in[0];
  const float* mask = (const float*)d_in[1];
  const float* Wqkv = (const float*)d_in[2];
  const float* bqkv = (const float*)d_in[3];
  const float* Wo   = (const float*)d_in[4];
  const float* bo   = (const float*)d_in[5];
  float* out = (float*)d_out;
  char* ws = (char*)d_ws;

  u16* hsb   = (u16*)(ws);                 // 8 MB [4096][1024]
  u16* Wqkvt = (u16*)(ws + (8  << 20));    // 6 MB [3072][1024]
  u16* Wot   = (u16*)(ws + (14 << 20));    // 2 MB [1024][1024]
  u16* Qb    = (u16*)(ws + (16 << 20));    // 8 MB [2,16,2048,64]
  u16* Kb    = (u16*)(ws + (24 << 20));    // 8 MB [2,16,2048,64]
  u32* flags = (u32*)(ws + (32 << 20));    // 8 KB [2][32][32]
  u16* Vtb   = (u16*)(ws + (40 << 20));    // 8 MB [2,16,64,2048]
  u16* AOb   = (u16*)(ws + (48 << 20));    // 8 MB [4096][1024]

  k_convert<<<2048, 256, 0, stream>>>(hs, hsb, 4096 * 1024);
  k_tconv<<<dim3(3072 / 64, 1024 / 64), 256, 0, stream>>>(Wqkv, Wqkvt, 1024, 3072);
  k_tconv<<<dim3(1024 / 64, 1024 / 64), 256, 0, stream>>>(Wo, Wot, 1024, 1024);
  k_maskflags<<<2048, 256, 0, stream>>>(mask, flags);
  k_gemm<0, 128><<<dim3(24, 32), 256, 0, stream>>>(hsb, Wqkvt, 4096, 3072, 1024, bqkv,
                                                   Qb, Kb, Vtb, nullptr);
  k_attn<<<512, 256, 0, stream>>>(Qb, Kb, Vtb, mask, flags, AOb);
  k_gemm<1, 64><<<dim3(8, 64), 256, 0, stream>>>(AOb, Wot, 4096, 1024, 1024, bo,
                                                 nullptr, nullptr, nullptr, out);
}

// Round 9
// 127.849 us; speedup vs baseline: 1.8944x; 1.0729x over previous
//
#include <hip/hip_runtime.h>
#include <hip/hip_bf16.h>
#include <cstdint>
#include <cstddef>

typedef __attribute__((ext_vector_type(8))) short short8;
typedef __attribute__((ext_vector_type(4))) float f32x4;
typedef __attribute__((ext_vector_type(16))) float f32x16;
typedef unsigned short u16;
typedef unsigned int u32;

#define B_ 2
#define C_ 2048
#define D_ 1024
#define H_ 16
#define HD_ 64

static __device__ __forceinline__ u16 f2b(float f) {
  u32 x = __builtin_bit_cast(u32, f);
  x += 0x7FFFu + ((x >> 16) & 1u);
  return (u16)(x >> 16);
}
static __device__ __forceinline__ float b2f(u16 v) {
  return __builtin_bit_cast(float, (u32)v << 16);
}

// ---------------- plain convert f32 -> bf16 ----------------
__global__ void k_convert(const float* __restrict__ in, u16* __restrict__ out, int n) {
  int i = (blockIdx.x * blockDim.x + threadIdx.x) * 4;
  const int stride = gridDim.x * blockDim.x * 4;
  for (; i < n; i += stride) {
    float4 v = *reinterpret_cast<const float4*>(in + i);
    ushort4 o;
    o.x = f2b(v.x); o.y = f2b(v.y); o.z = f2b(v.z); o.w = f2b(v.w);
    *reinterpret_cast<ushort4*>(out + i) = o;
  }
}

// ---------------- transpose + convert: in[R][Cc] f32 -> out[Cc][R] bf16 ----------------
__global__ void k_tconv(const float* __restrict__ in, u16* __restrict__ out, int R, int Cc) {
  __shared__ float tile[64][65];
  const int tC = blockIdx.x * 64;
  const int tR = blockIdx.y * 64;
  const int t = threadIdx.x;
  const int r0 = t >> 4;         // 0..15
  const int c0 = (t & 15) * 4;   // 0..60
#pragma unroll
  for (int ii = 0; ii < 4; ++ii) {
    int r = ii * 16 + r0;
    float4 v = *reinterpret_cast<const float4*>(&in[(size_t)(tR + r) * Cc + tC + c0]);
    tile[r][c0] = v.x; tile[r][c0 + 1] = v.y; tile[r][c0 + 2] = v.z; tile[r][c0 + 3] = v.w;
  }
  __syncthreads();
#pragma unroll
  for (int ii = 0; ii < 4; ++ii) {
    int c = ii * 16 + r0;  // output row (= input col)
    ushort4 o;
    o.x = f2b(tile[c0 + 0][c]);
    o.y = f2b(tile[c0 + 1][c]);
    o.z = f2b(tile[c0 + 2][c]);
    o.w = f2b(tile[c0 + 3][c]);
    *reinterpret_cast<ushort4*>(&out[(size_t)(tC + c) * R + tR + c0]) = o;
  }
}

// ---------------- per-tile (64q x 64k) mask nonzero flags ----------------
// bid = b*1024 + qs*32 + kt
__global__ void k_maskflags(const float* __restrict__ mask, u32* __restrict__ flags) {
  const int bid = blockIdx.x;
  const int kt = bid & 31, qs = (bid >> 5) & 31, b = bid >> 10;
  const int t = threadIdx.x;
  const float* base = mask + ((size_t)b * C_ + qs * 64) * C_ + kt * 64;
  const int row = t >> 2, c0 = (t & 3) * 16;
  int any = 0;
#pragma unroll
  for (int i = 0; i < 4; ++i) {
    float4 v = *reinterpret_cast<const float4*>(base + (size_t)row * C_ + c0 + i * 4);
    any |= (v.x != 0.f) | (v.y != 0.f) | (v.z != 0.f) | (v.w != 0.f);
  }
  __shared__ int sh[4];
  const unsigned long long bal = __ballot(any);
  if ((t & 63) == 0) sh[t >> 6] = (bal != 0ull);
  __syncthreads();
  if (t == 0) flags[bid] = (u32)(sh[0] | sh[1] | sh[2] | sh[3]);
}

// ---------------- async global->LDS, 16B per lane ----------------
#define GLL16(gptr, lptr) __builtin_amdgcn_global_load_lds( \
    (const __attribute__((address_space(1))) u32*)(gptr),   \
    (__attribute__((address_space(3))) u32*)(lptr), 16, 0, 0)

// ---------------- BMx128 bf16 GEMM (BK=64, swizzled LDS), C = A * Bt^T + bias ----
// EPI 0: scatter Q/K -> [B,H,C,hd], V -> transposed [B,H,hd,C].  EPI 1: f32 C + bias.
template<int EPI, int BM>
__global__ __launch_bounds__(256) void k_gemm(
    const u16* __restrict__ A, const u16* __restrict__ Bt,
    int M, int N, int K, const float* __restrict__ bias,
    u16* __restrict__ Cq, u16* __restrict__ Ck, u16* __restrict__ Cv,
    float* __restrict__ Cf)
{
  constexpr int WCW = (BM == 128) ? 64 : 32;   // per-wave col width
  constexpr int NF = WCW / 16;                 // n-frags per wave
  __shared__ __align__(16) u16 As[BM * 64];
  __shared__ __align__(16) u16 Bs[128 * 64];
  const int t = threadIdx.x;
  const int l = t & 63, w = t >> 6;
  const int wr = (BM == 128) ? (w >> 1) : 0;
  const int wc = (BM == 128) ? (w & 1) : w;
  const int lr = l & 15, lg = l >> 4;
  const int swk = lr & 7;
  const int m0 = blockIdx.y * BM, n0 = blockIdx.x * 128;
  f32x4 acc[4][NF] = {};

  for (int k0 = 0; k0 < K; k0 += 64) {
#pragma unroll
    for (int s = 0; s < BM / 32; ++s) {        // A: BM*8 16B-units
      const int u = s * 256 + t;
      const int row = u >> 3, slot = (u & 7) ^ (row & 7);
      GLL16(A + (size_t)(m0 + row) * K + k0 + (slot << 3), As + (u << 3));
    }
#pragma unroll
    for (int s = 0; s < 4; ++s) {              // B: 1024 16B-units
      const int u = s * 256 + t;
      const int row = u >> 3, slot = (u & 7) ^ (row & 7);
      GLL16(Bt + (size_t)(n0 + row) * K + k0 + (slot << 3), Bs + (u << 3));
    }
    __syncthreads();
    short8 af[2][4], bfr[2][NF];
#pragma unroll
    for (int s = 0; s < 2; ++s) {
#pragma unroll
      for (int m = 0; m < 4; ++m)
        af[s][m] = *reinterpret_cast<const short8*>(
            &As[((wr * 64 + m * 16 + lr) << 6) + (((s * 4 + lg) ^ swk) << 3)]);
#pragma unroll
      for (int n = 0; n < NF; ++n)
        bfr[s][n] = *reinterpret_cast<const short8*>(
            &Bs[((wc * WCW + n * 16 + lr) << 6) + (((s * 4 + lg) ^ swk) << 3)]);
    }
#pragma unroll
    for (int s = 0; s < 2; ++s)
#pragma unroll
      for (int m = 0; m < 4; ++m)
#pragma unroll
        for (int n = 0; n < NF; ++n)
          acc[m][n] = __builtin_amdgcn_mfma_f32_16x16x32_bf16(af[s][m], bfr[s][n], acc[m][n], 0, 0, 0);
    __syncthreads();
  }

#pragma unroll
  for (int m = 0; m < 4; ++m) {
    const int mg = m0 + wr * 64 + m * 16 + lg * 4;
    const int bq = mg >> 11, c0 = mg & 2047;
#pragma unroll
    for (int n = 0; n < NF; ++n) {
      const int ng = n0 + wc * WCW + n * 16 + lr;
      const float bia = bias[ng];
      if (EPI == 0) {
        const int reg = ng >> 10, d = ng & 1023, h = d >> 6, e = d & 63;
        if (reg == 2) {
          u16* vp = Cv + (((size_t)(bq * H_ + h) * HD_ + e) << 11) + c0;  // [B,H,hd,C]
#pragma unroll
          for (int j = 0; j < 4; ++j) vp[j] = f2b(acc[m][n][j] + bia);
        } else {
          u16* dst = (reg == 0) ? Cq : Ck;
#pragma unroll
          for (int j = 0; j < 4; ++j)
            dst[(((size_t)(bq * H_ + h) * C_ + c0 + j) << 6) + e] = f2b(acc[m][n][j] + bia);
        }
      } else {
#pragma unroll
        for (int j = 0; j < 4; ++j)
          Cf[(size_t)(mg + j) * N + ng] = acc[m][n][j] + bia;
      }
    }
  }
}

// stage one K tile [64 keys][64 hd] and one Vt tile [64 hd][64 keys] via DMA.
// LDS linear dest; source 16B-slot pre-XOR-swizzled (T21): slot ^= row&7.
static __device__ __forceinline__ void stage_kv(
    const u16* __restrict__ Kbh, const u16* __restrict__ Vbh,
    u16* Kd, u16* Vd, int kt, int t)
{
#pragma unroll
  for (int ch = 0; ch < 2; ++ch) {
    const int u = ch * 256 + t;
    const int row = u >> 3, slot = (u & 7) ^ (row & 7);
    GLL16(Kbh + (((size_t)(kt * 64 + row)) << 6) + (slot << 3), Kd + (u << 3));
    GLL16(Vbh + (((size_t)row) << 11) + kt * 64 + (slot << 3), Vd + (u << 3));
  }
}

// ---------------- causal flash attention (v8: v6 + minimal 16-tile split) ------------
// grid: 768 = 24 segs x 32 bh (longest-first; bid%8 == bh%8 -> XCD-local K/V).
// qt 0..7: one segment, direct normalized output (identical to verified v6 path).
// qt 8..15: two segments (tiles 0..15 / 16..ntiles); each writes NORMALIZED partial
// Ohat = O/l (bf16, same epilogue as direct) + (m,l) f32; k_merge combines.
__global__ __launch_bounds__(256) void k_attn(
    const u16* __restrict__ Q, const u16* __restrict__ Kb, const u16* __restrict__ Vt,
    const float* __restrict__ mask, const u32* __restrict__ flags,
    u16* __restrict__ O, u16* __restrict__ Opart, float2* __restrict__ ml)
{
  __shared__ __align__(16) u16 Kl[2][64 * 64];
  __shared__ __align__(16) u16 Vl[2][64 * 64];
  __shared__ __align__(16) u16 Sc[4][2304];   // per-warp: P [32][64] (4KB) / Ol 32x144B
  const int bid = blockIdx.x;
  const int bh = bid & 31;                    // bid%8 == bh%8 -> XCD-local K/V
  const int sidx = 23 - (bid >> 5);           // longest segments dispatch first
  int qt, seg, nseg;
  if (sidx < 8) { qt = sidx; seg = 0; nseg = 1; }
  else          { const int u = sidx - 8; qt = 8 + (u >> 1); seg = u & 1; nseg = 2; }
  const int ntiles = 2 * qt + 2;
  const int kt0 = seg * 16;                   // even -> prologue buffer parity ok
  const int kt1 = seg ? ntiles : ((ntiles < 16) ? ntiles : 16);
  const int slot = ((bh << 3) + (qt - 8)) * 2 + seg;   // valid when nseg==2

  const int b = bh >> 4, h = bh & 15;
  const int t = threadIdx.x;
  const int l = t & 63, w = t >> 6;
  const int q = l & 31, hi = l >> 5;
  const int q7 = q & 7;

  const u16* Kbh = Kb + (size_t)bh * (C_ * HD_);
  const u16* Vbh = Vt + (size_t)bh * (HD_ * C_);
  char* Swb = reinterpret_cast<char*>(Sc[w]);

  const int q0w = qt * 128 + w * 32;
  const int qg = q0w + q;
  const int qmaxw = q0w + 31;

  // Q frags (B-operand: lane q=lane&31, k-slice=8*hi+i), pre-scaled by hd^-0.5
  short8 aq[4];
  {
    const u16* qp = Q + ((size_t)bh * C_ + qg) * HD_ + hi * 8;
#pragma unroll
    for (int kh = 0; kh < 4; ++kh) {
      short8 v = *reinterpret_cast<const short8*>(qp + kh * 16);
#pragma unroll
      for (int i = 0; i < 8; ++i) {
        const float f = b2f((u16)v[i]) * 0.125f;
        v[i] = (short)f2b(f);
      }
      aq[kh] = v;
    }
  }

  f32x16 oa0 = {}, oa1 = {};
  float mrun = -INFINITY, srun = 0.f;
  const float* mrow = mask + ((size_t)b * C_ + qg) * C_;
  const u32* fb = flags + (size_t)(b * 32 + (q0w >> 6)) * 32;

  stage_kv(Kbh, Vbh, Kl[0], Vl[0], kt0, t);

#pragma unroll 1
  for (int kt = kt0; kt < kt1; ++kt) {
    const int cur = kt & 1;
    __syncthreads();                        // drains own vmcnt + fence + barrier
    if (kt + 1 < kt1) stage_kv(Kbh, Vbh, Kl[cur ^ 1], Vl[cur ^ 1], kt + 1, t);
    if (kt * 64 > qmaxw) continue;          // warp fully past-causal for this tile

    const char* Kc = reinterpret_cast<const char*>(Kl[cur]);
    const char* Vc = reinterpret_cast<const char*>(Vl[cur]);

    // S^T = K Q^T : D[key][q]; p0 = keys kt*64+[0,32), p1 = +[32,64)
    f32x16 p0 = {}, p1 = {};
#pragma unroll
    for (int kh = 0; kh < 4; ++kh) {
      const int sl = ((2 * kh + hi) ^ q7) << 4;
      const short8 k0 = *reinterpret_cast<const short8*>(Kc + q * 128 + sl);
      const short8 k1 = *reinterpret_cast<const short8*>(Kc + (32 + q) * 128 + sl);
      p0 = __builtin_amdgcn_mfma_f32_32x32x16_bf16(k0, aq[kh], p0, 0, 0, 0);
      p1 = __builtin_amdgcn_mfma_f32_32x32x16_bf16(k1, aq[kh], p1, 0, 0, 0);
    }

    // additive mask (only when tile nonzero)
    if (fb[kt]) {
      const float* mp = mrow + kt * 64 + 4 * hi;
#pragma unroll
      for (int g = 0; g < 4; ++g) {
        const float4 m0 = *reinterpret_cast<const float4*>(mp + 8 * g);
        const float4 m1 = *reinterpret_cast<const float4*>(mp + 32 + 8 * g);
        p0[4*g+0] += m0.x; p0[4*g+1] += m0.y; p0[4*g+2] += m0.z; p0[4*g+3] += m0.w;
        p1[4*g+0] += m1.x; p1[4*g+1] += m1.y; p1[4*g+2] += m1.z; p1[4*g+3] += m1.w;
      }
    }
    // causal clamp (diagonal region only)
    if (kt * 64 + 63 > q0w) {
#pragma unroll
      for (int r = 0; r < 16; ++r) {
        const int kl = kt * 64 + (r & 3) + 8 * (r >> 2) + 4 * hi;
        if (kl > qg) p0[r] = -INFINITY;
        if (kl + 32 > qg) p1[r] = -INFINITY;
      }
    }

    // online softmax: in-lane over 32 scores + one cross-half shfl.
    float pm = -INFINITY;
#pragma unroll
    for (int r = 0; r < 16; ++r) pm = fmaxf(pm, fmaxf(p0[r], p1[r]));
    pm = fmaxf(pm, __shfl_xor(pm, 32));
    const float mn = fmaxf(fmaxf(mrun, pm), -1e30f);
    const float rs = __expf(mrun - mn);     // first iter: exp(-inf)=0
    float sum = 0.f;
#pragma unroll
    for (int r = 0; r < 16; ++r) {
      p0[r] = __expf(p0[r] - mn); sum += p0[r];
      p1[r] = __expf(p1[r] - mn); sum += p1[r];
    }
    sum += __shfl_xor(sum, 32);
    srun = srun * rs + sum;
    mrun = mn;
    oa0 *= rs; oa1 *= rs;

    // P -> per-warp LDS [32 q][64 keys], 16B-slot swizzled by q&7
#pragma unroll
    for (int g = 0; g < 4; ++g) {
#pragma unroll
      for (int m = 0; m < 2; ++m) {
        u32 w0, w1;
        asm("v_cvt_pk_bf16_f32 %0, %1, %2" : "=v"(w0) : "v"(p0[4*g+2*m]), "v"(p0[4*g+2*m+1]));
        asm("v_cvt_pk_bf16_f32 %0, %1, %2" : "=v"(w1) : "v"(p1[4*g+2*m]), "v"(p1[4*g+2*m+1]));
        *reinterpret_cast<u32*>(Swb + q * 128 + ((g ^ q7) << 4) + 8 * hi + 4 * m) = w0;
        *reinterpret_cast<u32*>(Swb + q * 128 + (((4 + g) ^ q7) << 4) + 8 * hi + 4 * m) = w1;
      }
    }
    asm volatile("" ::: "memory");          // order same-wave LDS write -> read

    // O^T += Vt x P : D[d][q]
#pragma unroll
    for (int ks = 0; ks < 4; ++ks) {
      const int sl = ((2 * ks + hi) ^ q7) << 4;
      const short8 bp = *reinterpret_cast<const short8*>(Swb + q * 128 + sl);
      const short8 v0 = *reinterpret_cast<const short8*>(Vc + q * 128 + sl);
      const short8 v1 = *reinterpret_cast<const short8*>(Vc + (32 + q) * 128 + sl);
      oa0 = __builtin_amdgcn_mfma_f32_32x32x16_bf16(v0, bp, oa0, 0, 0, 0);
      oa1 = __builtin_amdgcn_mfma_f32_32x32x16_bf16(v1, bp, oa1, 0, 0, 0);
    }
  }

  // epilogue: normalize (both paths!), transpose via per-warp LDS, vector store
  const float rinv = 1.f / srun;
#pragma unroll
  for (int g = 0; g < 4; ++g) {
    const int d0 = 8 * g + 4 * hi;
    const float a0 = oa0[4*g+0] * rinv, a1 = oa0[4*g+1] * rinv;
    const float a2 = oa0[4*g+2] * rinv, a3 = oa0[4*g+3] * rinv;
    const float b0 = oa1[4*g+0] * rinv, b1 = oa1[4*g+1] * rinv;
    const float b2 = oa1[4*g+2] * rinv, b3 = oa1[4*g+3] * rinv;
    u32 w0, w1, w2, w3;
    asm("v_cvt_pk_bf16_f32 %0, %1, %2" : "=v"(w0) : "v"(a0), "v"(a1));
    asm("v_cvt_pk_bf16_f32 %0, %1, %2" : "=v"(w1) : "v"(a2), "v"(a3));
    asm("v_cvt_pk_bf16_f32 %0, %1, %2" : "=v"(w2) : "v"(b0), "v"(b1));
    asm("v_cvt_pk_bf16_f32 %0, %1, %2" : "=v"(w3) : "v"(b2), "v"(b3));
    *reinterpret_cast<uint2*>(Swb + q * 144 + d0 * 2) = make_uint2(w0, w1);
    *reinterpret_cast<uint2*>(Swb + q * 144 + (d0 + 32) * 2) = make_uint2(w2, w3);
  }
  asm volatile("" ::: "memory");            // order same-wave LDS write -> read
  const int q2 = l >> 1, hf = l & 1;
  if (nseg == 1) {
    u16* orow = O + ((size_t)b * C_ + q0w + q2) * D_ + h * 64 + hf * 32;
#pragma unroll
    for (int i = 0; i < 4; ++i) {
      const short8 v = *reinterpret_cast<const short8*>(Swb + q2 * 144 + hf * 64 + i * 16);
      *reinterpret_cast<short8*>(orow + i * 8) = v;
    }
  } else {
    u16* prow = Opart + (((size_t)slot * 128 + w * 32 + q2) << 6) + hf * 32;
#pragma unroll
    for (int i = 0; i < 4; ++i) {
      const short8 v = *reinterpret_cast<const short8*>(Swb + q2 * 144 + hf * 64 + i * 16);
      *reinterpret_cast<short8*>(prow + i * 8) = v;
    }
    if (hi == 0) ml[(size_t)slot * 128 + w * 32 + q] = make_float2(mrun, srun);
  }
}

// ---------------- merge split-KV partials (nseg == 2) ----------------
// grid 256 = 8 qt (8..15) x 32 bh; 256 thr: thread -> (q = t>>1, dhalf = t&1)
// Partials are NORMALIZED: O = (a0*Ohat0 + a1*Ohat1)/(a0+a1), a_s = e^{m_s-M} l_s
__global__ __launch_bounds__(256) void k_merge(
    const u16* __restrict__ Opart, const float2* __restrict__ ml, u16* __restrict__ O)
{
  const int bid = blockIdx.x;
  const int bh = bid & 31;
  const int qt = 8 + (bid >> 5);
  const int slot0 = ((bh << 3) + (qt - 8)) * 2;
  const int b = bh >> 4, h = bh & 15;
  const int t = threadIdx.x;
  const int q = t >> 1, dh = t & 1;

  const float2 v0 = ml[(size_t)slot0 * 128 + q];
  const float2 v1 = ml[(size_t)(slot0 + 1) * 128 + q];
  const float M = fmaxf(v0.x, v1.x);
  const float a0 = __expf(v0.x - M) * v0.y;
  const float a1 = __expf(v1.x - M) * v1.y;
  const float rT = 1.f / (a0 + a1);
  const float r0 = a0 * rT, r1 = a1 * rT;

  const u16* p0 = Opart + (((size_t)slot0 * 128 + q) << 6) + dh * 32;
  const u16* p1 = Opart + (((size_t)(slot0 + 1) * 128 + q) << 6) + dh * 32;
  u16* orow = O + ((size_t)b * C_ + qt * 128 + q) * D_ + h * 64 + dh * 32;
#pragma unroll
  for (int i = 0; i < 4; ++i) {
    const short8 x0 = *reinterpret_cast<const short8*>(p0 + i * 8);
    const short8 x1 = *reinterpret_cast<const short8*>(p1 + i * 8);
    short8 y;
#pragma unroll
    for (int j = 0; j < 8; ++j)
      y[j] = (short)f2b(r0 * b2f((u16)x0[j]) + r1 * b2f((u16)x1[j]));
    *reinterpret_cast<short8*>(orow + i * 8) = y;
  }
}

extern "C" void kernel_launch(void* const* d_in, const int* in_sizes, int n_in,
                              void* d_out, int out_size, void* d_ws, size_t ws_size,
                              hipStream_t stream) {
  const float* hs   = (const float*)d_in[0];
  const float* mask = (const float*)d_in[1];
  const float* Wqkv = (const float*)d_in[2];
  const float* bqkv = (const float*)d_in[3];
  const float* Wo   = (const float*)d_in[4];
  const float* bo   = (const float*)d_in[5];
  float* out = (float*)d_out;
  char* ws = (char*)d_ws;

  // time-phased layout (peak 56 MB):
  u16*    hsb   = (u16*)(ws);                   // 8 MB, dead after gemm0
  u16*    Opart = (u16*)(ws);                   // 8 MB, attn phase (overlays hsb)
  u16*    Wqkvt = (u16*)(ws + (8  << 20));      // 6 MB
  float2* mlbuf = (float2*)(ws + (19 << 20));   // 512 KB [512 slots][128]
  u32*    flags = (u32*)(ws + (20 << 20) + (1 << 19)); // 8 KB @20.5MB
  u16*    Wot   = (u16*)(ws + (21 << 20));      // 2 MB
  u16*    Qb    = (u16*)(ws + (24 << 20));      // 8 MB [2,16,2048,64]
  u16*    Kb    = (u16*)(ws + (32 << 20));      // 8 MB [2,16,2048,64]
  u16*    Vtb   = (u16*)(ws + (40 << 20));      // 8 MB [2,16,64,2048]
  u16*    AOb   = (u16*)(ws + (48 << 20));      // 8 MB [4096][1024]

  k_convert<<<2048, 256, 0, stream>>>(hs, hsb, 4096 * 1024);
  k_tconv<<<dim3(3072 / 64, 1024 / 64), 256, 0, stream>>>(Wqkv, Wqkvt, 1024, 3072);
  k_tconv<<<dim3(1024 / 64, 1024 / 64), 256, 0, stream>>>(Wo, Wot, 1024, 1024);
  k_maskflags<<<2048, 256, 0, stream>>>(mask, flags);
  k_gemm<0, 128><<<dim3(24, 32), 256, 0, stream>>>(hsb, Wqkvt, 4096, 3072, 1024, bqkv,
                                                   Qb, Kb, Vtb, nullptr);
  k_attn<<<768, 256, 0, stream>>>(Qb, Kb, Vtb, mask, flags, AOb, Opart, mlbuf);
  k_merge<<<256, 256, 0, stream>>>(Opart, mlbuf, AOb);
  k_gemm<1, 64><<<dim3(8, 64), 256, 0, stream>>>(AOb, Wot, 4096, 1024, 1024, bo,
                                                 nullptr, nullptr, nullptr, out);
}